// Round 1
// baseline (1199.559 us; speedup 1.0000x reference)
//
#include <hip/hip_runtime.h>

#define S 64
#define CLS 14
#define NBOX 46
#define BATCH 64
#define NEG 0.01f
#define EPS 1e-5f

// ---------------------------------------------------------------- render ----
__global__ __launch_bounds__(256) void render_kernel(const float* __restrict__ in,
                                                     float* __restrict__ out) {
    int b = blockIdx.x;
    __shared__ float r0[NBOX], r1[NBOX], r2[NBOX], r3[NBOX];
    __shared__ float cls_s[NBOX * CLS];
    int tid = threadIdx.x;
    if (tid < NBOX) {
        const float* p = in + ((size_t)b * NBOX + tid) * (CLS + 4) + CLS;
        float x = p[0] * S, y = p[1] * S, w = p[2] * S, h = p[3] * S;
        r0[tid] = x - 0.5f * w; r1[tid] = x + 0.5f * w;
        r2[tid] = y - 0.5f * h; r3[tid] = y + 0.5f * h;
    }
    for (int idx = tid; idx < NBOX * CLS; idx += 256) {
        int n = idx / CLS, c = idx % CLS;
        cls_s[idx] = in[((size_t)b * NBOX + n) * (CLS + 4) + c];
    }
    __syncthreads();
    for (int pp = 0; pp < (S * S) / 256; ++pp) {
        int pix = tid + pp * 256;
        float cx = (float)(pix & 63);
        float cy = (float)(pix >> 6);
        float acc[CLS];
#pragma unroll
        for (int c = 0; c < CLS; ++c) acc[c] = 0.f;
        for (int n = 0; n < NBOX; ++n) {
            float x0 = r0[n], x1 = r1[n], y0 = r2[n], y1 = r3[n];
            float by = fminf(fmaxf(cy - y0, 0.f), 1.f) * fminf(fmaxf(y1 - cy, 0.f), 1.f);
            float bx = fminf(fmaxf(cx - x0, 0.f), 1.f) * fminf(fmaxf(x1 - cx, 0.f), 1.f);
            float kx0 = fmaxf(1.f - fabsf(cx - x0), 0.f);
            float kx1 = fmaxf(1.f - fabsf(cx - x1), 0.f);
            float ky0 = fmaxf(1.f - fabsf(cy - y0), 0.f);
            float ky1 = fmaxf(1.f - fabsf(cy - y1), 0.f);
            float r = fmaxf(fmaxf(kx0 * by, kx1 * by), fmaxf(ky0 * bx, ky1 * bx));
            if (r > 0.f) {
#pragma unroll
                for (int c = 0; c < CLS; ++c) acc[c] = fmaf(cls_s[n * CLS + c], r, acc[c]);
            }
        }
#pragma unroll
        for (int c = 0; c < CLS; ++c)
            out[((size_t)b * CLS + c) * (S * S) + pix] = acc[c];
    }
}

// ---------------------------------------------------- direct 5x5 s2 conv ----
// Block: BPB batches x all HOUT*HOUT pixels, COB output channels.
// Input plane staged (zero-padded, pad=2) in LDS per ci; weights read via
// block-uniform addresses -> scalar loads -> SGPR operands on the FMAs.
template <int CIN, int COUT, int HIN, int HOUT, int COB, int BPB, int PPT>
__global__ __launch_bounds__(256) void conv5x5_s2(const float* __restrict__ in,
                                                  const float* __restrict__ w,
                                                  float* __restrict__ out) {
    constexpr int HP = HIN + 4;
    constexpr int NGCO = COUT / COB;
    __shared__ float plane[BPB][HP * HP];
    int tid = threadIdx.x;
    int co_base = (blockIdx.x % NGCO) * COB;
    int bg = blockIdx.x / NGCO;

    for (int i = tid; i < BPB * HP * HP; i += 256) ((float*)plane)[i] = 0.f;
    __syncthreads();

    float acc[PPT][COB];
#pragma unroll
    for (int p = 0; p < PPT; ++p)
#pragma unroll
        for (int j = 0; j < COB; ++j) acc[p][j] = 0.f;

    for (int ci = 0; ci < CIN; ++ci) {
#pragma unroll
        for (int bs = 0; bs < BPB; ++bs) {
            const float* src = in + ((size_t)(bg * BPB + bs) * CIN + ci) * (HIN * HIN);
            for (int i = tid; i < HIN * HIN; i += 256) {
                int r = i / HIN, c = i % HIN;
                plane[bs][(r + 2) * HP + (c + 2)] = src[i];
            }
        }
        __syncthreads();
#pragma unroll
        for (int kh = 0; kh < 5; ++kh) {
            float wl[COB * 5];
#pragma unroll
            for (int j = 0; j < COB; ++j)
#pragma unroll
                for (int kw = 0; kw < 5; ++kw)
                    wl[j * 5 + kw] = w[((size_t)(co_base + j) * CIN + ci) * 25 + kh * 5 + kw];
#pragma unroll
            for (int p = 0; p < PPT; ++p) {
                int pix = tid + p * 256;
                int bs = pix / (HOUT * HOUT);
                int ohw = pix % (HOUT * HOUT);
                int oh = ohw / HOUT, ow = ohw % HOUT;
                const float* lp = &plane[bs][(oh * 2 + kh) * HP + ow * 2];
#pragma unroll
                for (int kw = 0; kw < 5; ++kw) {
                    float v = lp[kw];
#pragma unroll
                    for (int j = 0; j < COB; ++j)
                        acc[p][j] = fmaf(v, wl[j * 5 + kw], acc[p][j]);
                }
            }
        }
        __syncthreads();
    }
#pragma unroll
    for (int p = 0; p < PPT; ++p) {
        int pix = tid + p * 256;
        int bs = pix / (HOUT * HOUT);
        int ohw = pix % (HOUT * HOUT);
        int b = bg * BPB + bs;
#pragma unroll
        for (int j = 0; j < COB; ++j)
            out[((size_t)b * COUT + co_base + j) * (HOUT * HOUT) + ohw] = acc[p][j];
    }
}

// ----------------------------------------------------------- batch stats ----
// One block per channel. Computes scale/shift for training-mode BN.
__global__ __launch_bounds__(256) void stats_kernel(const float* __restrict__ X,
                                                    const float* __restrict__ gamma,
                                                    const float* __restrict__ beta,
                                                    float* __restrict__ stats,
                                                    int C, int log2HW) {
    int c = blockIdx.x;
    int HW = 1 << log2HW;
    int n = BATCH * HW;
    float s = 0.f, s2 = 0.f;
    for (int idx = threadIdx.x; idx < n; idx += 256) {
        int b = idx >> log2HW;
        int i = idx & (HW - 1);
        float v = X[(((size_t)b * C + c) << log2HW) + i];
        s += v; s2 += v * v;
    }
#pragma unroll
    for (int off = 32; off > 0; off >>= 1) {
        s  += __shfl_down(s, off);
        s2 += __shfl_down(s2, off);
    }
    __shared__ float ls[4], ls2[4];
    int wid = threadIdx.x >> 6, lane = threadIdx.x & 63;
    if (lane == 0) { ls[wid] = s; ls2[wid] = s2; }
    __syncthreads();
    if (threadIdx.x == 0) {
        s = ls[0] + ls[1] + ls[2] + ls[3];
        s2 = ls2[0] + ls2[1] + ls2[2] + ls2[3];
        float mean = s / n;
        float var = fmaxf(s2 / n - mean * mean, 0.f);
        float sc = gamma[c] * rsqrtf(var + EPS);
        float sh = beta[c] - mean * sc;
        stats[2 * c] = sc;
        stats[2 * c + 1] = sh;
    }
}

// ------------------------------------------------------------- BN+lrelu -----
__global__ __launch_bounds__(256) void bn_lrelu_kernel(float* __restrict__ X,
                                                       const float* __restrict__ stats,
                                                       int Cmask, int log2HW, int total) {
    int idx = blockIdx.x * 256 + threadIdx.x;
    if (idx >= total) return;
    int c = (idx >> log2HW) & Cmask;
    float sc = stats[2 * c], sh = stats[2 * c + 1];
    float y = fmaf(X[idx], sc, sh);
    X[idx] = y >= 0.f ? y : NEG * y;
}

// -------------------------------------------------- conv4 as split-K GEMM ---
// A: [64][16384] (normalized h3), W: [1024][16384], out: [64][1024] atomic-acc
__global__ __launch_bounds__(256) void conv4_gemm(const float* __restrict__ A,
                                                  const float* __restrict__ W,
                                                  float* __restrict__ out) {
    __shared__ float a_s[16][68];
    __shared__ float b_s[16][68];
    int tid = threadIdx.x;
    int cot = blockIdx.x & 15;
    int ks  = blockIdx.x >> 4;
    int co_base = cot * 64;
    float acc[4][4];
#pragma unroll
    for (int i = 0; i < 4; ++i)
#pragma unroll
        for (int j = 0; j < 4; ++j) acc[i][j] = 0.f;

    int lrow = tid >> 2;          // 0..63
    int lk4  = (tid & 3) * 4;     // 0,4,8,12
    int b0 = (tid & 15) * 4;
    int c0 = (tid >> 4) * 4;

    int kbeg = ks * 1024;
    for (int k0 = kbeg; k0 < kbeg + 1024; k0 += 16) {
        float4 av = *(const float4*)&A[(size_t)lrow * 16384 + k0 + lk4];
        float4 bv = *(const float4*)&W[(size_t)(co_base + lrow) * 16384 + k0 + lk4];
        a_s[lk4 + 0][lrow] = av.x; a_s[lk4 + 1][lrow] = av.y;
        a_s[lk4 + 2][lrow] = av.z; a_s[lk4 + 3][lrow] = av.w;
        b_s[lk4 + 0][lrow] = bv.x; b_s[lk4 + 1][lrow] = bv.y;
        b_s[lk4 + 2][lrow] = bv.z; b_s[lk4 + 3][lrow] = bv.w;
        __syncthreads();
#pragma unroll
        for (int kk = 0; kk < 16; ++kk) {
            float4 a4 = *(const float4*)&a_s[kk][b0];
            float4 b4 = *(const float4*)&b_s[kk][c0];
            float av_[4] = {a4.x, a4.y, a4.z, a4.w};
            float bv_[4] = {b4.x, b4.y, b4.z, b4.w};
#pragma unroll
            for (int i = 0; i < 4; ++i)
#pragma unroll
                for (int j = 0; j < 4; ++j)
                    acc[i][j] = fmaf(av_[i], bv_[j], acc[i][j]);
        }
        __syncthreads();
    }
#pragma unroll
    for (int i = 0; i < 4; ++i)
#pragma unroll
        for (int j = 0; j < 4; ++j)
            atomicAdd(&out[(size_t)(b0 + i) * 1024 + co_base + c0 + j], acc[i][j]);
}

// ----------------------------------------------------------------- conv5 ----
__global__ __launch_bounds__(256) void conv5_kernel(const float* __restrict__ X,
                                                    const float* __restrict__ w5,
                                                    const float* __restrict__ b5,
                                                    float* __restrict__ out) {
    int b = blockIdx.x;
    int tid = threadIdx.x;
    float s = 0.f;
    for (int c = tid; c < 1024; c += 256) s = fmaf(X[(size_t)b * 1024 + c], w5[c], s);
#pragma unroll
    for (int off = 32; off > 0; off >>= 1) s += __shfl_down(s, off);
    __shared__ float ls[4];
    int wid = tid >> 6, lane = tid & 63;
    if (lane == 0) ls[wid] = s;
    __syncthreads();
    if (tid == 0) out[b] = ls[0] + ls[1] + ls[2] + ls[3] + b5[0];
}

// ----------------------------------------------------------------- launch ---
extern "C" void kernel_launch(void* const* d_in, const int* in_sizes, int n_in,
                              void* d_out, int out_size, void* d_ws, size_t ws_size,
                              hipStream_t stream) {
    (void)in_sizes; (void)n_in; (void)out_size; (void)ws_size;
    const float* input_data = (const float*)d_in[0];
    const float* w1 = (const float*)d_in[2];
    const float* g1 = (const float*)d_in[3];
    const float* b1 = (const float*)d_in[4];
    const float* w2 = (const float*)d_in[5];
    const float* g2 = (const float*)d_in[6];
    const float* b2 = (const float*)d_in[7];
    const float* w3 = (const float*)d_in[8];
    const float* g3 = (const float*)d_in[9];
    const float* b3 = (const float*)d_in[10];
    const float* w4 = (const float*)d_in[11];
    const float* g4 = (const float*)d_in[12];
    const float* b4 = (const float*)d_in[13];
    const float* w5 = (const float*)d_in[14];
    const float* b5 = (const float*)d_in[15];

    char* ws = (char*)d_ws;
    float* bufA = (float*)ws;                                   // 14,680,064 B (rendered / h2)
    float* bufB = (float*)(ws + 14680064);                      // 16,777,216 B (h1 / h3)
    float* h4   = (float*)(ws + 14680064 + 16777216);           //    262,144 B
    float* st   = (float*)(ws + 14680064 + 16777216 + 262144);  //      8,192 B

    hipMemsetAsync(h4, 0, 64 * 1024 * sizeof(float), stream);

    render_kernel<<<64, 256, 0, stream>>>(input_data, bufA);

    // conv1: 14 -> 64, 64x64 -> 32x32
    conv5x5_s2<14, 64, 64, 32, 8, 1, 4><<<512, 256, 0, stream>>>(bufA, w1, bufB);
    stats_kernel<<<64, 256, 0, stream>>>(bufB, g1, b1, st, 64, 10);
    bn_lrelu_kernel<<<4194304 / 256, 256, 0, stream>>>(bufB, st, 63, 10, 4194304);

    // conv2: 64 -> 128, 32x32 -> 16x16
    conv5x5_s2<64, 128, 32, 16, 8, 1, 1><<<1024, 256, 0, stream>>>(bufB, w2, bufA);
    stats_kernel<<<128, 256, 0, stream>>>(bufA, g2, b2, st, 128, 8);
    bn_lrelu_kernel<<<2097152 / 256, 256, 0, stream>>>(bufA, st, 127, 8, 2097152);

    // conv3: 128 -> 256, 16x16 -> 8x8
    conv5x5_s2<128, 256, 16, 8, 8, 4, 1><<<512, 256, 0, stream>>>(bufA, w3, bufB);
    stats_kernel<<<256, 256, 0, stream>>>(bufB, g3, b3, st, 256, 6);
    bn_lrelu_kernel<<<1048576 / 256, 256, 0, stream>>>(bufB, st, 255, 6, 1048576);

    // conv4: [64,256,8,8] x [1024,256,8,8] -> [64,1024]  (split-K GEMM)
    conv4_gemm<<<256, 256, 0, stream>>>(bufB, w4, h4);
    stats_kernel<<<1024, 256, 0, stream>>>(h4, g4, b4, st, 1024, 0);
    bn_lrelu_kernel<<<65536 / 256, 256, 0, stream>>>(h4, st, 1023, 0, 65536);

    // conv5: 1x1
    conv5_kernel<<<64, 256, 0, stream>>>(h4, w5, b5, (float*)d_out);
}

// Round 2
// 473.412 us; speedup vs baseline: 2.5339x; 2.5339x over previous
//
#include <hip/hip_runtime.h>
#include <hip/hip_bf16.h>

#define NEG 0.01f
#define EPS 1e-5f

typedef __attribute__((ext_vector_type(8))) short short8;
typedef __attribute__((ext_vector_type(4))) float floatx4;

__device__ inline unsigned short f2bf(float f) {
    __hip_bfloat16 h = __float2bfloat16(f);
    union { __hip_bfloat16 h; unsigned short u; } cv; cv.h = h;
    return cv.u;
}

// ---------------------------------------------------------------- render ----
// Writes padded NHWC bf16: [64][68][68][16]; borders & ch14/15 stay 0 (memset).
__global__ __launch_bounds__(256) void render_kernel(const float* __restrict__ in,
                                                     unsigned short* __restrict__ out) {
    int b = blockIdx.x;
    __shared__ float r0[46], r1[46], r2[46], r3[46];
    __shared__ float cls_s[46 * 14];
    int tid = threadIdx.x;
    if (tid < 46) {
        const float* p = in + ((size_t)b * 46 + tid) * 18 + 14;
        float x = p[0] * 64.f, y = p[1] * 64.f, w = p[2] * 64.f, h = p[3] * 64.f;
        r0[tid] = x - 0.5f * w; r1[tid] = x + 0.5f * w;
        r2[tid] = y - 0.5f * h; r3[tid] = y + 0.5f * h;
    }
    for (int idx = tid; idx < 46 * 14; idx += 256) {
        int n = idx / 14, c = idx % 14;
        cls_s[idx] = in[((size_t)b * 46 + n) * 18 + c];
    }
    __syncthreads();
    for (int pp = 0; pp < 16; ++pp) {
        int pix = tid + pp * 256;
        float cx = (float)(pix & 63);
        float cy = (float)(pix >> 6);
        float acc[14];
#pragma unroll
        for (int c = 0; c < 14; ++c) acc[c] = 0.f;
        for (int n = 0; n < 46; ++n) {
            float x0 = r0[n], x1 = r1[n], y0 = r2[n], y1 = r3[n];
            float by = fminf(fmaxf(cy - y0, 0.f), 1.f) * fminf(fmaxf(y1 - cy, 0.f), 1.f);
            float bx = fminf(fmaxf(cx - x0, 0.f), 1.f) * fminf(fmaxf(x1 - cx, 0.f), 1.f);
            float kx0 = fmaxf(1.f - fabsf(cx - x0), 0.f);
            float kx1 = fmaxf(1.f - fabsf(cx - x1), 0.f);
            float ky0 = fmaxf(1.f - fabsf(cy - y0), 0.f);
            float ky1 = fmaxf(1.f - fabsf(cy - y1), 0.f);
            float r = fmaxf(fmaxf(kx0 * by, kx1 * by), fmaxf(ky0 * bx, ky1 * bx));
            if (r > 0.f) {
#pragma unroll
                for (int c = 0; c < 14; ++c) acc[c] = fmaf(cls_s[n * 14 + c], r, acc[c]);
            }
        }
        size_t base = (((size_t)b * 68 + ((pix >> 6) + 2)) * 68 + ((pix & 63) + 2)) * 16;
#pragma unroll
        for (int c = 0; c < 14; ++c) out[base + c] = f2bf(acc[c]);
    }
}

// ----------------------------------------------------- weight transform -----
// wT[step=kh*SUB+sub][co][kk32] = w[co][ci][kh][kw], kidx=sub*32+kk, kw=kidx>>CPLOG,
// ci=kidx&(CP-1); zero if kw>=5 or ci>=CIN.
__global__ __launch_bounds__(256) void wtrans_kernel(const float* __restrict__ w,
                                                     unsigned short* __restrict__ wT,
                                                     int CIN, int CPLOG, int SUB,
                                                     int COLOG, int total) {
    int idx = blockIdx.x * 256 + threadIdx.x;
    if (idx >= total) return;
    int kk = idx & 31;
    int co = (idx >> 5) & ((1 << COLOG) - 1);
    int s = idx >> (5 + COLOG);
    int kh = s / SUB, sub = s % SUB;
    int kidx = sub * 32 + kk;
    int kw = kidx >> CPLOG;
    int ci = kidx & ((1 << CPLOG) - 1);
    float v = (kw < 5 && ci < CIN) ? w[((size_t)(co * CIN + ci) * 5 + kh) * 5 + kw] : 0.f;
    wT[idx] = f2bf(v);
}

// ------------------------------------------- implicit-GEMM MFMA conv --------
// inP: padded NHWC bf16 [B][HP][HP][CP]. Block = 64 px x 64 co. 4 waves,
// each wave 16px x 64co via 4x mfma_f32_16x16x32_bf16 per 32-K step.
template <int CP, int COUT, int HP, int LOG_OHW, int LOG_OW, int SUB, int NCO>
__global__ __launch_bounds__(256) void conv_mfma(const unsigned short* __restrict__ inP,
                                                 const unsigned short* __restrict__ wT,
                                                 float* __restrict__ outX) {
    __shared__ short As[64][40];
    __shared__ short Bs[64][40];
    int tid = threadIdx.x;
    int bm = blockIdx.x / NCO;
    int bco = blockIdx.x % NCO;
    int r = tid >> 2, cc = tid & 3;
    int m = bm * 64 + r;
    int b = m >> LOG_OHW;
    int ohw = m & ((1 << LOG_OHW) - 1);
    int oh = ohw >> LOG_OW;
    int ow = ohw & ((1 << LOG_OW) - 1);
    const short* ag0 = (const short*)inP + ((size_t)((b * HP + 2 * oh) * HP + 2 * ow)) * CP + cc * 8;
    const short* bg0 = (const short*)wT + (size_t)(bco * 64 + r) * 32 + cc * 8;
    int wave = tid >> 6, lane = tid & 63, q = lane >> 4, l16 = lane & 15;
    const short* afp = &As[wave * 16 + l16][q * 8];
    const short* bfp = &Bs[l16][q * 8];
    floatx4 acc[4];
#pragma unroll
    for (int nt = 0; nt < 4; ++nt) acc[nt] = (floatx4){0.f, 0.f, 0.f, 0.f};

    int step = 0;
    for (int kh = 0; kh < 5; ++kh) {
        const short* agh = ag0 + kh * HP * CP;
        for (int sub = 0; sub < SUB; ++sub, ++step) {
            short8 av = *(const short8*)(agh + sub * 32);
            short8 bv = *(const short8*)(bg0 + (size_t)step * COUT * 32);
            *(short8*)&As[r][cc * 8] = av;
            *(short8*)&Bs[r][cc * 8] = bv;
            __syncthreads();
            short8 af = *(const short8*)afp;
#pragma unroll
            for (int nt = 0; nt < 4; ++nt) {
                short8 bf = *(const short8*)(bfp + nt * 16 * 40);
                acc[nt] = __builtin_amdgcn_mfma_f32_16x16x32_bf16(af, bf, acc[nt], 0, 0, 0);
            }
            __syncthreads();
        }
    }
#pragma unroll
    for (int nt = 0; nt < 4; ++nt) {
#pragma unroll
        for (int rg = 0; rg < 4; ++rg) {
            int mg = bm * 64 + wave * 16 + q * 4 + rg;
            int co = bco * 64 + nt * 16 + l16;
            outX[(size_t)mg * COUT + co] = acc[nt][rg];
        }
    }
}

// --------------------------------------------------- conv4 split-K GEMM -----
// A: bf16 [64][16384] (NCHW flat), B: w4 fp32 [1024][16384] cast on the fly.
__global__ __launch_bounds__(256) void conv4_mfma(const unsigned short* __restrict__ A,
                                                  const float* __restrict__ w4,
                                                  float* __restrict__ h4) {
    __shared__ short As[64][40];
    __shared__ short Bs[64][40];
    int tid = threadIdx.x;
    int bco = blockIdx.x & 15;
    int ks = blockIdx.x >> 4;
    int r = tid >> 2, cc = tid & 3;
    const short* ag0 = (const short*)A + (size_t)r * 16384 + ks * 1024 + cc * 8;
    const float* bg0 = w4 + (size_t)(bco * 64 + r) * 16384 + ks * 1024 + cc * 8;
    int wave = tid >> 6, lane = tid & 63, q = lane >> 4, l16 = lane & 15;
    floatx4 acc[4];
#pragma unroll
    for (int nt = 0; nt < 4; ++nt) acc[nt] = (floatx4){0.f, 0.f, 0.f, 0.f};

    for (int s = 0; s < 32; ++s) {
        short8 av = *(const short8*)(ag0 + s * 32);
        float4 b0 = *(const float4*)(bg0 + s * 32);
        float4 b1 = *(const float4*)(bg0 + s * 32 + 4);
        short8 bv;
        bv[0] = (short)f2bf(b0.x); bv[1] = (short)f2bf(b0.y);
        bv[2] = (short)f2bf(b0.z); bv[3] = (short)f2bf(b0.w);
        bv[4] = (short)f2bf(b1.x); bv[5] = (short)f2bf(b1.y);
        bv[6] = (short)f2bf(b1.z); bv[7] = (short)f2bf(b1.w);
        *(short8*)&As[r][cc * 8] = av;
        *(short8*)&Bs[r][cc * 8] = bv;
        __syncthreads();
        short8 af = *(const short8*)&As[wave * 16 + l16][q * 8];
#pragma unroll
        for (int nt = 0; nt < 4; ++nt) {
            short8 bf = *(const short8*)&Bs[nt * 16 + l16][q * 8];
            acc[nt] = __builtin_amdgcn_mfma_f32_16x16x32_bf16(af, bf, acc[nt], 0, 0, 0);
        }
        __syncthreads();
    }
#pragma unroll
    for (int nt = 0; nt < 4; ++nt) {
#pragma unroll
        for (int rg = 0; rg < 4; ++rg) {
            int mg = wave * 16 + q * 4 + rg;
            int co = bco * 64 + nt * 16 + l16;
            atomicAdd(&h4[(size_t)mg * 1024 + co], acc[nt][rg]);
        }
    }
}

// ----------------------------------------------------------- batch stats ----
// X: NHWC fp32 [R][CO]; partial sums atomically into acc[0..CO-1]=s, [CO..]=s2.
__global__ __launch_bounds__(256) void stats_part(const float* __restrict__ X,
                                                  float* __restrict__ acc,
                                                  int CO, int R, int RPB, int CGLOG) {
    int tid = threadIdx.x;
    int cg = blockIdx.x & ((1 << CGLOG) - 1);
    int rb = blockIdx.x >> CGLOG;
    int c = (cg << 6) + (tid & 63);
    int w = tid >> 6;
    float s = 0.f, s2 = 0.f;
    int rend = min(R, (rb + 1) * RPB);
    for (int r = rb * RPB + w; r < rend; r += 4) {
        float v = X[(size_t)r * CO + c];
        s += v; s2 += v * v;
    }
    __shared__ float ls[4][64], ls2[4][64];
    ls[w][tid & 63] = s; ls2[w][tid & 63] = s2;
    __syncthreads();
    if (tid < 64) {
        float ts = ls[0][tid] + ls[1][tid] + ls[2][tid] + ls[3][tid];
        float ts2 = ls2[0][tid] + ls2[1][tid] + ls2[2][tid] + ls2[3][tid];
        int cc = (cg << 6) + tid;
        atomicAdd(&acc[cc], ts);
        atomicAdd(&acc[CO + cc], ts2);
    }
}

__global__ __launch_bounds__(256) void bn_finalize(const float* __restrict__ acc,
                                                   const float* __restrict__ g,
                                                   const float* __restrict__ bb,
                                                   float* __restrict__ st,
                                                   int CO, float invN) {
    int c = blockIdx.x * 256 + threadIdx.x;
    if (c >= CO) return;
    float mean = acc[c] * invN;
    float var = fmaxf(acc[CO + c] * invN - mean * mean, 0.f);
    float sc = g[c] * rsqrtf(var + EPS);
    st[c] = sc;
    st[CO + c] = bb[c] - mean * sc;
}

// ---------------------------------- BN + lrelu + pad + bf16 (NHWC->NHWC) ----
__global__ __launch_bounds__(256) void bnpad_kernel(const float* __restrict__ X,
                                                    const float* __restrict__ st,
                                                    unsigned short* __restrict__ out,
                                                    int CO_LOG, int OH, int OHP, int total) {
    int idx = blockIdx.x * 256 + threadIdx.x;
    if (idx >= total) return;
    int c = idx & ((1 << CO_LOG) - 1);
    int t = idx >> CO_LOG;
    int x = t % OHP; t /= OHP;
    int y = t % OHP; int b = t / OHP;
    unsigned short v = 0;
    if (y >= 2 && y < OH + 2 && x >= 2 && x < OH + 2) {
        float f = X[(((size_t)(b * OH + (y - 2)) * OH + (x - 2)) << CO_LOG) + c];
        f = f * st[c] + st[(1 << CO_LOG) + c];
        f = f >= 0.f ? f : NEG * f;
        v = f2bf(f);
    }
    out[idx] = v;
}

// ------------------------- BN + lrelu + bf16, NHWC -> NCHW (conv4 input) ----
__global__ __launch_bounds__(256) void bn_nchw_kernel(const float* __restrict__ X,
                                                      const float* __restrict__ st,
                                                      unsigned short* __restrict__ out,
                                                      int total) {
    int idx = blockIdx.x * 256 + threadIdx.x;
    if (idx >= total) return;
    int hw = idx & 63;
    int ci = (idx >> 6) & 255;
    int b = idx >> 14;
    float f = X[((size_t)(b * 64 + hw)) * 256 + ci];
    f = f * st[ci] + st[256 + ci];
    f = f >= 0.f ? f : NEG * f;
    out[idx] = f2bf(f);
}

// ------------------------------------------------- conv5 (fused BN4) --------
__global__ __launch_bounds__(256) void conv5_kernel(const float* __restrict__ X,
                                                    const float* __restrict__ st,
                                                    const float* __restrict__ w5,
                                                    const float* __restrict__ b5,
                                                    float* __restrict__ out) {
    int b = blockIdx.x, tid = threadIdx.x;
    float s = 0.f;
    for (int c = tid; c < 1024; c += 256) {
        float f = X[(size_t)b * 1024 + c] * st[c] + st[1024 + c];
        f = f >= 0.f ? f : NEG * f;
        s = fmaf(f, w5[c], s);
    }
#pragma unroll
    for (int off = 32; off > 0; off >>= 1) s += __shfl_down(s, off);
    __shared__ float ls[4];
    if ((tid & 63) == 0) ls[tid >> 6] = s;
    __syncthreads();
    if (tid == 0) out[b] = ls[0] + ls[1] + ls[2] + ls[3] + b5[0];
}

// ----------------------------------------------------------------- launch ---
extern "C" void kernel_launch(void* const* d_in, const int* in_sizes, int n_in,
                              void* d_out, int out_size, void* d_ws, size_t ws_size,
                              hipStream_t stream) {
    (void)in_sizes; (void)n_in; (void)out_size; (void)ws_size;
    const float* input_data = (const float*)d_in[0];
    const float* w1 = (const float*)d_in[2];
    const float* g1 = (const float*)d_in[3];
    const float* b1 = (const float*)d_in[4];
    const float* w2 = (const float*)d_in[5];
    const float* g2 = (const float*)d_in[6];
    const float* b2 = (const float*)d_in[7];
    const float* w3 = (const float*)d_in[8];
    const float* g3 = (const float*)d_in[9];
    const float* b3 = (const float*)d_in[10];
    const float* w4 = (const float*)d_in[11];
    const float* g4 = (const float*)d_in[12];
    const float* b4 = (const float*)d_in[13];
    const float* w5 = (const float*)d_in[14];
    const float* b5 = (const float*)d_in[15];

    char* ws = (char*)d_ws;
    // regionA (16.8 MB): conv1out fp32, later conv3out fp32
    float* regA = (float*)ws;
    char* wsB = ws + 16777216;              // regionB (10.7 MB): pad1, later pad2
    char* wsC = wsB + 10616832;             // regionC (9.5 MB): rendered, conv2out, a4
    char* wsD = wsC + 9469952;
    float* h4 = (float*)wsD;                                    // 262144
    float* stacc = (float*)(wsD + 262144);                      // 8192
    float* st = (float*)(wsD + 270336);                         // 8192
    unsigned short* wT1 = (unsigned short*)(wsD + 278528);      // 61440
    unsigned short* wT2 = (unsigned short*)(wsD + 339968);      // 409600
    unsigned short* wT3 = (unsigned short*)(wsD + 749568);      // 1638400

    unsigned short* rendered = (unsigned short*)wsC;
    float* conv1out = regA;
    unsigned short* pad1 = (unsigned short*)wsB;
    float* conv2out = (float*)wsC;
    unsigned short* pad2 = (unsigned short*)wsB;
    float* conv3out = regA;
    unsigned short* a4 = (unsigned short*)wsC;

    // weight transforms
    wtrans_kernel<<<120, 256, 0, stream>>>(w1, wT1, 14, 4, 3, 6, 30720);
    wtrans_kernel<<<800, 256, 0, stream>>>(w2, wT2, 64, 6, 10, 7, 204800);
    wtrans_kernel<<<3200, 256, 0, stream>>>(w3, wT3, 128, 7, 20, 8, 819200);

    hipMemsetAsync(rendered, 0, 9469952, stream);
    hipMemsetAsync(h4, 0, 262144, stream);

    render_kernel<<<64, 256, 0, stream>>>(input_data, rendered);

    // conv1: [64,16p,68,68] -> [65536,64]
    conv_mfma<16, 64, 68, 10, 5, 3, 1><<<1024, 256, 0, stream>>>(rendered, wT1, conv1out);
    hipMemsetAsync(stacc, 0, 8192, stream);
    stats_part<<<128, 256, 0, stream>>>(conv1out, stacc, 64, 65536, 512, 0);
    bn_finalize<<<1, 256, 0, stream>>>(stacc, g1, b1, st, 64, 1.f / 65536.f);
    bnpad_kernel<<<20736, 256, 0, stream>>>(conv1out, st, pad1, 6, 32, 36, 5308416);

    // conv2: [64,64,36,36p] -> [16384,128]
    conv_mfma<64, 128, 36, 8, 4, 10, 2><<<512, 256, 0, stream>>>(pad1, wT2, conv2out);
    hipMemsetAsync(stacc, 0, 8192, stream);
    stats_part<<<256, 256, 0, stream>>>(conv2out, stacc, 128, 16384, 128, 1);
    bn_finalize<<<1, 256, 0, stream>>>(stacc, g2, b2, st, 128, 1.f / 16384.f);
    bnpad_kernel<<<12800, 256, 0, stream>>>(conv2out, st, pad2, 7, 16, 20, 3276800);

    // conv3: [64,128,20,20p] -> [4096,256]
    conv_mfma<128, 256, 20, 6, 3, 20, 4><<<256, 256, 0, stream>>>(pad2, wT3, conv3out);
    hipMemsetAsync(stacc, 0, 8192, stream);
    stats_part<<<512, 256, 0, stream>>>(conv3out, stacc, 256, 4096, 32, 2);
    bn_finalize<<<1, 256, 0, stream>>>(stacc, g3, b3, st, 256, 1.f / 4096.f);
    bn_nchw_kernel<<<4096, 256, 0, stream>>>(conv3out, st, a4, 1048576);

    // conv4: [64,16384] x [1024,16384]^T -> [64,1024], split-K=16
    conv4_mfma<<<256, 256, 0, stream>>>(a4, w4, h4);
    hipMemsetAsync(stacc, 0, 8192, stream);
    stats_part<<<16, 256, 0, stream>>>(h4, stacc, 1024, 64, 64, 4);
    bn_finalize<<<4, 256, 0, stream>>>(stacc, g4, b4, st, 1024, 1.f / 64.f);

    // conv5 (fused BN4 + lrelu)
    conv5_kernel<<<64, 256, 0, stream>>>(h4, st, w5, b5, (float*)d_out);
}

// Round 3
// 372.140 us; speedup vs baseline: 3.2234x; 1.2721x over previous
//
#include <hip/hip_runtime.h>
#include <hip/hip_bf16.h>

#define NEG 0.01f
#define EPS 1e-5f

typedef __attribute__((ext_vector_type(8))) short short8;
typedef __attribute__((ext_vector_type(4))) float floatx4;

__device__ inline unsigned short f2bf(float f) {
    __hip_bfloat16 h = __float2bfloat16(f);
    union { __hip_bfloat16 h; unsigned short u; } cv; cv.h = h;
    return cv.u;
}

// ---------------------------------------------------------------- render ----
// Writes padded NHWC bf16: [64][68][68][16]; borders & ch14/15 stay 0 (memset).
// 1024 blocks = 64 batches x 16 chunks; one pixel per thread.
__global__ __launch_bounds__(256) void render_kernel(const float* __restrict__ in,
                                                     unsigned short* __restrict__ out) {
    int b = blockIdx.x >> 4;
    int chunk = blockIdx.x & 15;
    __shared__ float r0[46], r1[46], r2[46], r3[46];
    __shared__ float cls_s[46 * 14];
    int tid = threadIdx.x;
    if (tid < 46) {
        const float* p = in + ((size_t)b * 46 + tid) * 18 + 14;
        float x = p[0] * 64.f, y = p[1] * 64.f, w = p[2] * 64.f, h = p[3] * 64.f;
        r0[tid] = x - 0.5f * w; r1[tid] = x + 0.5f * w;
        r2[tid] = y - 0.5f * h; r3[tid] = y + 0.5f * h;
    }
    for (int idx = tid; idx < 46 * 14; idx += 256) {
        int n = idx / 14, c = idx % 14;
        cls_s[idx] = in[((size_t)b * 46 + n) * 18 + c];
    }
    __syncthreads();
    int pix = chunk * 256 + tid;
    float cx = (float)(pix & 63);
    float cy = (float)(pix >> 6);
    float acc[14];
#pragma unroll
    for (int c = 0; c < 14; ++c) acc[c] = 0.f;
    for (int n = 0; n < 46; ++n) {
        float x0 = r0[n], x1 = r1[n], y0 = r2[n], y1 = r3[n];
        float by = fminf(fmaxf(cy - y0, 0.f), 1.f) * fminf(fmaxf(y1 - cy, 0.f), 1.f);
        float bx = fminf(fmaxf(cx - x0, 0.f), 1.f) * fminf(fmaxf(x1 - cx, 0.f), 1.f);
        float kx0 = fmaxf(1.f - fabsf(cx - x0), 0.f);
        float kx1 = fmaxf(1.f - fabsf(cx - x1), 0.f);
        float ky0 = fmaxf(1.f - fabsf(cy - y0), 0.f);
        float ky1 = fmaxf(1.f - fabsf(cy - y1), 0.f);
        float r = fmaxf(fmaxf(kx0 * by, kx1 * by), fmaxf(ky0 * bx, ky1 * bx));
        if (r > 0.f) {
#pragma unroll
            for (int c = 0; c < 14; ++c) acc[c] = fmaf(cls_s[n * 14 + c], r, acc[c]);
        }
    }
    size_t base = (((size_t)b * 68 + ((pix >> 6) + 2)) * 68 + ((pix & 63) + 2)) * 16;
#pragma unroll
    for (int c = 0; c < 14; ++c) out[base + c] = f2bf(acc[c]);
}

// ----------------------------------------------------- weight transform -----
// wT[step=kh*SUB+sub][co][kk32] = w[co][ci][kh][kw], kidx=sub*32+kk, kw=kidx>>CPLOG,
// ci=kidx&(CP-1); zero if kw>=5 or ci>=CIN.
__global__ __launch_bounds__(256) void wtrans_kernel(const float* __restrict__ w,
                                                     unsigned short* __restrict__ wT,
                                                     int CIN, int CPLOG, int SUB,
                                                     int COLOG, int total) {
    int idx = blockIdx.x * 256 + threadIdx.x;
    if (idx >= total) return;
    int kk = idx & 31;
    int co = (idx >> 5) & ((1 << COLOG) - 1);
    int s = idx >> (5 + COLOG);
    int kh = s / SUB, sub = s % SUB;
    int kidx = sub * 32 + kk;
    int kw = kidx >> CPLOG;
    int ci = kidx & ((1 << CPLOG) - 1);
    float v = (kw < 5 && ci < CIN) ? w[((size_t)(co * CIN + ci) * 5 + kh) * 5 + kw] : 0.f;
    wT[idx] = f2bf(v);
}

// ------------------------------------------- implicit-GEMM MFMA conv --------
// inP: padded NHWC bf16 [B][HP][HP][CP]. Block = 64 px x 64 co. 4 waves,
// each wave 16px x 64co via 4x mfma_f32_16x16x32_bf16 per 32-K step.
template <int CP, int COUT, int HP, int LOG_OHW, int LOG_OW, int SUB, int NCO>
__global__ __launch_bounds__(256) void conv_mfma(const unsigned short* __restrict__ inP,
                                                 const unsigned short* __restrict__ wT,
                                                 float* __restrict__ outX) {
    __shared__ short As[64][40];
    __shared__ short Bs[64][40];
    int tid = threadIdx.x;
    int bm = blockIdx.x / NCO;
    int bco = blockIdx.x % NCO;
    int r = tid >> 2, cc = tid & 3;
    int m = bm * 64 + r;
    int b = m >> LOG_OHW;
    int ohw = m & ((1 << LOG_OHW) - 1);
    int oh = ohw >> LOG_OW;
    int ow = ohw & ((1 << LOG_OW) - 1);
    const short* ag0 = (const short*)inP + ((size_t)((b * HP + 2 * oh) * HP + 2 * ow)) * CP + cc * 8;
    const short* bg0 = (const short*)wT + (size_t)(bco * 64 + r) * 32 + cc * 8;
    int wave = tid >> 6, lane = tid & 63, q = lane >> 4, l16 = lane & 15;
    const short* afp = &As[wave * 16 + l16][q * 8];
    const short* bfp = &Bs[l16][q * 8];
    floatx4 acc[4];
#pragma unroll
    for (int nt = 0; nt < 4; ++nt) acc[nt] = (floatx4){0.f, 0.f, 0.f, 0.f};

    int step = 0;
    for (int kh = 0; kh < 5; ++kh) {
        const short* agh = ag0 + kh * HP * CP;
        for (int sub = 0; sub < SUB; ++sub, ++step) {
            short8 av = *(const short8*)(agh + sub * 32);
            short8 bv = *(const short8*)(bg0 + (size_t)step * COUT * 32);
            *(short8*)&As[r][cc * 8] = av;
            *(short8*)&Bs[r][cc * 8] = bv;
            __syncthreads();
            short8 af = *(const short8*)afp;
#pragma unroll
            for (int nt = 0; nt < 4; ++nt) {
                short8 bf = *(const short8*)(bfp + nt * 16 * 40);
                acc[nt] = __builtin_amdgcn_mfma_f32_16x16x32_bf16(af, bf, acc[nt], 0, 0, 0);
            }
            __syncthreads();
        }
    }
#pragma unroll
    for (int nt = 0; nt < 4; ++nt) {
#pragma unroll
        for (int rg = 0; rg < 4; ++rg) {
            int mg = bm * 64 + wave * 16 + q * 4 + rg;
            int co = bco * 64 + nt * 16 + l16;
            outX[(size_t)mg * COUT + co] = acc[nt][rg];
        }
    }
}

// --------------------------------------------------- conv4 split-K GEMM -----
// A: bf16 [64][16384] (NCHW flat), B: w4 fp32 [1024][16384] cast on the fly.
__global__ __launch_bounds__(256) void conv4_mfma(const unsigned short* __restrict__ A,
                                                  const float* __restrict__ w4,
                                                  float* __restrict__ h4) {
    __shared__ short As[64][40];
    __shared__ short Bs[64][40];
    int tid = threadIdx.x;
    int bco = blockIdx.x & 15;
    int ks = blockIdx.x >> 4;
    int r = tid >> 2, cc = tid & 3;
    const short* ag0 = (const short*)A + (size_t)r * 16384 + ks * 1024 + cc * 8;
    const float* bg0 = w4 + (size_t)(bco * 64 + r) * 16384 + ks * 1024 + cc * 8;
    int wave = tid >> 6, lane = tid & 63, q = lane >> 4, l16 = lane & 15;
    floatx4 acc[4];
#pragma unroll
    for (int nt = 0; nt < 4; ++nt) acc[nt] = (floatx4){0.f, 0.f, 0.f, 0.f};

    for (int s = 0; s < 32; ++s) {
        short8 av = *(const short8*)(ag0 + s * 32);
        float4 b0 = *(const float4*)(bg0 + s * 32);
        float4 b1 = *(const float4*)(bg0 + s * 32 + 4);
        short8 bv;
        bv[0] = (short)f2bf(b0.x); bv[1] = (short)f2bf(b0.y);
        bv[2] = (short)f2bf(b0.z); bv[3] = (short)f2bf(b0.w);
        bv[4] = (short)f2bf(b1.x); bv[5] = (short)f2bf(b1.y);
        bv[6] = (short)f2bf(b1.z); bv[7] = (short)f2bf(b1.w);
        *(short8*)&As[r][cc * 8] = av;
        *(short8*)&Bs[r][cc * 8] = bv;
        __syncthreads();
        short8 af = *(const short8*)&As[wave * 16 + l16][q * 8];
#pragma unroll
        for (int nt = 0; nt < 4; ++nt) {
            short8 bf = *(const short8*)&Bs[nt * 16 + l16][q * 8];
            acc[nt] = __builtin_amdgcn_mfma_f32_16x16x32_bf16(af, bf, acc[nt], 0, 0, 0);
        }
        __syncthreads();
    }
#pragma unroll
    for (int nt = 0; nt < 4; ++nt) {
#pragma unroll
        for (int rg = 0; rg < 4; ++rg) {
            int mg = wave * 16 + q * 4 + rg;
            int co = bco * 64 + nt * 16 + l16;
            atomicAdd(&h4[(size_t)mg * 1024 + co], acc[nt][rg]);
        }
    }
}

// ----------------------------------------------------------- batch stats ----
// X: NHWC fp32 [R][CO]; partial sums atomically into acc[0..CO-1]=s, [CO..]=s2.
__global__ __launch_bounds__(256) void stats_part(const float* __restrict__ X,
                                                  float* __restrict__ acc,
                                                  int CO, int R, int RPB, int CGLOG) {
    int tid = threadIdx.x;
    int cg = blockIdx.x & ((1 << CGLOG) - 1);
    int rb = blockIdx.x >> CGLOG;
    int c = (cg << 6) + (tid & 63);
    int w = tid >> 6;
    float s = 0.f, s2 = 0.f;
    int rend = min(R, (rb + 1) * RPB);
    for (int r = rb * RPB + w; r < rend; r += 4) {
        float v = X[(size_t)r * CO + c];
        s += v; s2 += v * v;
    }
    __shared__ float ls[4][64], ls2[4][64];
    ls[w][tid & 63] = s; ls2[w][tid & 63] = s2;
    __syncthreads();
    if (tid < 64) {
        float ts = ls[0][tid] + ls[1][tid] + ls[2][tid] + ls[3][tid];
        float ts2 = ls2[0][tid] + ls2[1][tid] + ls2[2][tid] + ls2[3][tid];
        int cc = (cg << 6) + tid;
        atomicAdd(&acc[cc], ts);
        atomicAdd(&acc[CO + cc], ts2);
    }
}

__global__ __launch_bounds__(256) void bn_finalize(const float* __restrict__ acc,
                                                   const float* __restrict__ g,
                                                   const float* __restrict__ bb,
                                                   float* __restrict__ st,
                                                   int CO, float invN) {
    int c = blockIdx.x * 256 + threadIdx.x;
    if (c >= CO) return;
    float mean = acc[c] * invN;
    float var = fmaxf(acc[CO + c] * invN - mean * mean, 0.f);
    float sc = g[c] * rsqrtf(var + EPS);
    st[c] = sc;
    st[CO + c] = bb[c] - mean * sc;
}

// ---------------------------------- BN + lrelu + pad + bf16 (NHWC->NHWC) ----
__global__ __launch_bounds__(256) void bnpad_kernel(const float* __restrict__ X,
                                                    const float* __restrict__ st,
                                                    unsigned short* __restrict__ out,
                                                    int CO_LOG, int OH, int OHP, int total) {
    int idx = blockIdx.x * 256 + threadIdx.x;
    if (idx >= total) return;
    int c = idx & ((1 << CO_LOG) - 1);
    int t = idx >> CO_LOG;
    int x = t % OHP; t /= OHP;
    int y = t % OHP; int b = t / OHP;
    unsigned short v = 0;
    if (y >= 2 && y < OH + 2 && x >= 2 && x < OH + 2) {
        float f = X[(((size_t)(b * OH + (y - 2)) * OH + (x - 2)) << CO_LOG) + c];
        f = f * st[c] + st[(1 << CO_LOG) + c];
        f = f >= 0.f ? f : NEG * f;
        v = f2bf(f);
    }
    out[idx] = v;
}

// ------------------------- BN + lrelu + bf16, NHWC -> NCHW (conv4 input) ----
__global__ __launch_bounds__(256) void bn_nchw_kernel(const float* __restrict__ X,
                                                      const float* __restrict__ st,
                                                      unsigned short* __restrict__ out,
                                                      int total) {
    int idx = blockIdx.x * 256 + threadIdx.x;
    if (idx >= total) return;
    int hw = idx & 63;
    int ci = (idx >> 6) & 255;
    int b = idx >> 14;
    float f = X[((size_t)(b * 64 + hw)) * 256 + ci];
    f = f * st[ci] + st[256 + ci];
    f = f >= 0.f ? f : NEG * f;
    out[idx] = f2bf(f);
}

// ------------------------------------------------- conv5 (fused BN4) --------
__global__ __launch_bounds__(256) void conv5_kernel(const float* __restrict__ X,
                                                    const float* __restrict__ st,
                                                    const float* __restrict__ w5,
                                                    const float* __restrict__ b5,
                                                    float* __restrict__ out) {
    int b = blockIdx.x, tid = threadIdx.x;
    float s = 0.f;
    for (int c = tid; c < 1024; c += 256) {
        float f = X[(size_t)b * 1024 + c] * st[c] + st[1024 + c];
        f = f >= 0.f ? f : NEG * f;
        s = fmaf(f, w5[c], s);
    }
#pragma unroll
    for (int off = 32; off > 0; off >>= 1) s += __shfl_down(s, off);
    __shared__ float ls[4];
    if ((tid & 63) == 0) ls[tid >> 6] = s;
    __syncthreads();
    if (tid == 0) out[b] = ls[0] + ls[1] + ls[2] + ls[3] + b5[0];
}

// ----------------------------------------------------------------- launch ---
extern "C" void kernel_launch(void* const* d_in, const int* in_sizes, int n_in,
                              void* d_out, int out_size, void* d_ws, size_t ws_size,
                              hipStream_t stream) {
    (void)in_sizes; (void)n_in; (void)out_size; (void)ws_size;
    const float* input_data = (const float*)d_in[0];
    const float* w1 = (const float*)d_in[2];
    const float* g1 = (const float*)d_in[3];
    const float* b1 = (const float*)d_in[4];
    const float* w2 = (const float*)d_in[5];
    const float* g2 = (const float*)d_in[6];
    const float* b2 = (const float*)d_in[7];
    const float* w3 = (const float*)d_in[8];
    const float* g3 = (const float*)d_in[9];
    const float* b3 = (const float*)d_in[10];
    const float* w4 = (const float*)d_in[11];
    const float* g4 = (const float*)d_in[12];
    const float* b4 = (const float*)d_in[13];
    const float* w5 = (const float*)d_in[14];
    const float* b5 = (const float*)d_in[15];

    char* ws = (char*)d_ws;
    // regionA (16.8 MB): conv1out fp32, later conv3out fp32
    float* regA = (float*)ws;
    char* wsB = ws + 16777216;              // regionB (10.7 MB): pad1, later pad2
    char* wsC = wsB + 10616832;             // regionC (9.5 MB): rendered, conv2out, a4
    char* wsD = wsC + 9469952;
    float* h4 = (float*)wsD;                                    // 262144
    float* stacc = (float*)(wsD + 262144);                      // 8192
    float* st = (float*)(wsD + 270336);                         // 8192
    unsigned short* wT1 = (unsigned short*)(wsD + 278528);      // 61440
    unsigned short* wT2 = (unsigned short*)(wsD + 339968);      // 409600
    unsigned short* wT3 = (unsigned short*)(wsD + 749568);      // 1638400

    unsigned short* rendered = (unsigned short*)wsC;
    float* conv1out = regA;
    unsigned short* pad1 = (unsigned short*)wsB;
    float* conv2out = (float*)wsC;
    unsigned short* pad2 = (unsigned short*)wsB;
    float* conv3out = regA;
    unsigned short* a4 = (unsigned short*)wsC;

    // weight transforms
    wtrans_kernel<<<120, 256, 0, stream>>>(w1, wT1, 14, 4, 3, 6, 30720);
    wtrans_kernel<<<800, 256, 0, stream>>>(w2, wT2, 64, 6, 10, 7, 204800);
    wtrans_kernel<<<3200, 256, 0, stream>>>(w3, wT3, 128, 7, 20, 8, 819200);

    hipMemsetAsync(rendered, 0, 9469952, stream);
    hipMemsetAsync(h4, 0, 262144, stream);

    render_kernel<<<1024, 256, 0, stream>>>(input_data, rendered);

    // conv1: [64,16p,68,68] -> [65536,64]
    conv_mfma<16, 64, 68, 10, 5, 3, 1><<<1024, 256, 0, stream>>>(rendered, wT1, conv1out);
    hipMemsetAsync(stacc, 0, 8192, stream);
    stats_part<<<128, 256, 0, stream>>>(conv1out, stacc, 64, 65536, 512, 0);
    bn_finalize<<<1, 256, 0, stream>>>(stacc, g1, b1, st, 64, 1.f / 65536.f);
    bnpad_kernel<<<20736, 256, 0, stream>>>(conv1out, st, pad1, 6, 32, 36, 5308416);

    // conv2: [64,64,36,36p] -> [16384,128]
    conv_mfma<64, 128, 36, 8, 4, 10, 2><<<512, 256, 0, stream>>>(pad1, wT2, conv2out);
    hipMemsetAsync(stacc, 0, 8192, stream);
    stats_part<<<256, 256, 0, stream>>>(conv2out, stacc, 128, 16384, 128, 1);
    bn_finalize<<<1, 256, 0, stream>>>(stacc, g2, b2, st, 128, 1.f / 16384.f);
    bnpad_kernel<<<12800, 256, 0, stream>>>(conv2out, st, pad2, 7, 16, 20, 3276800);

    // conv3: [64,128,20,20p] -> [4096,256]
    conv_mfma<128, 256, 20, 6, 3, 20, 4><<<256, 256, 0, stream>>>(pad2, wT3, conv3out);
    hipMemsetAsync(stacc, 0, 8192, stream);
    stats_part<<<512, 256, 0, stream>>>(conv3out, stacc, 256, 4096, 32, 2);
    bn_finalize<<<1, 256, 0, stream>>>(stacc, g3, b3, st, 256, 1.f / 4096.f);
    bn_nchw_kernel<<<4096, 256, 0, stream>>>(conv3out, st, a4, 1048576);

    // conv4: [64,16384] x [1024,16384]^T -> [64,1024], split-K=16
    conv4_mfma<<<256, 256, 0, stream>>>(a4, w4, h4);
    hipMemsetAsync(stacc, 0, 8192, stream);
    stats_part<<<16, 256, 0, stream>>>(h4, stacc, 1024, 64, 64, 4);
    bn_finalize<<<4, 256, 0, stream>>>(stacc, g4, b4, st, 1024, 1.f / 64.f);

    // conv5 (fused BN4 + lrelu)
    conv5_kernel<<<64, 256, 0, stream>>>(h4, st, w5, b5, (float*)d_out);
}

// Round 4
// 311.792 us; speedup vs baseline: 3.8473x; 1.1936x over previous
//
#include <hip/hip_runtime.h>
#include <hip/hip_bf16.h>

#define NEG 0.01f
#define EPS 1e-5f

typedef __attribute__((ext_vector_type(8))) short short8;
typedef __attribute__((ext_vector_type(4))) float floatx4;

__device__ inline unsigned short f2bf(float f) {
    __hip_bfloat16 h = __float2bfloat16(f);
    union { __hip_bfloat16 h; unsigned short u; } cv; cv.h = h;
    return cv.u;
}

// ---------------------------------------------------------------- render ----
// Writes padded NHWC bf16: [64][68][68][16]; borders & ch14/15 stay 0 (memset).
// 1024 blocks = 64 batches x 16 chunks; one pixel per thread.
__global__ __launch_bounds__(256) void render_kernel(const float* __restrict__ in,
                                                     unsigned short* __restrict__ out) {
    int b = blockIdx.x >> 4;
    int chunk = blockIdx.x & 15;
    __shared__ float r0[46], r1[46], r2[46], r3[46];
    __shared__ float cls_s[46 * 14];
    int tid = threadIdx.x;
    if (tid < 46) {
        const float* p = in + ((size_t)b * 46 + tid) * 18 + 14;
        float x = p[0] * 64.f, y = p[1] * 64.f, w = p[2] * 64.f, h = p[3] * 64.f;
        r0[tid] = x - 0.5f * w; r1[tid] = x + 0.5f * w;
        r2[tid] = y - 0.5f * h; r3[tid] = y + 0.5f * h;
    }
    for (int idx = tid; idx < 46 * 14; idx += 256) {
        int n = idx / 14, c = idx % 14;
        cls_s[idx] = in[((size_t)b * 46 + n) * 18 + c];
    }
    __syncthreads();
    int pix = chunk * 256 + tid;
    float cx = (float)(pix & 63);
    float cy = (float)(pix >> 6);
    float acc[14];
#pragma unroll
    for (int c = 0; c < 14; ++c) acc[c] = 0.f;
    for (int n = 0; n < 46; ++n) {
        float x0 = r0[n], x1 = r1[n], y0 = r2[n], y1 = r3[n];
        float by = fminf(fmaxf(cy - y0, 0.f), 1.f) * fminf(fmaxf(y1 - cy, 0.f), 1.f);
        float bx = fminf(fmaxf(cx - x0, 0.f), 1.f) * fminf(fmaxf(x1 - cx, 0.f), 1.f);
        float kx0 = fmaxf(1.f - fabsf(cx - x0), 0.f);
        float kx1 = fmaxf(1.f - fabsf(cx - x1), 0.f);
        float ky0 = fmaxf(1.f - fabsf(cy - y0), 0.f);
        float ky1 = fmaxf(1.f - fabsf(cy - y1), 0.f);
        float r = fmaxf(fmaxf(kx0 * by, kx1 * by), fmaxf(ky0 * bx, ky1 * bx));
        if (r > 0.f) {
#pragma unroll
            for (int c = 0; c < 14; ++c) acc[c] = fmaf(cls_s[n * 14 + c], r, acc[c]);
        }
    }
    size_t base = (((size_t)b * 68 + ((pix >> 6) + 2)) * 68 + ((pix & 63) + 2)) * 16;
#pragma unroll
    for (int c = 0; c < 14; ++c) out[base + c] = f2bf(acc[c]);
}

// ----------------------------------------------------- weight transform -----
__global__ __launch_bounds__(256) void wtrans_kernel(const float* __restrict__ w,
                                                     unsigned short* __restrict__ wT,
                                                     int CIN, int CPLOG, int SUB,
                                                     int COLOG, int total) {
    int idx = blockIdx.x * 256 + threadIdx.x;
    if (idx >= total) return;
    int kk = idx & 31;
    int co = (idx >> 5) & ((1 << COLOG) - 1);
    int s = idx >> (5 + COLOG);
    int kh = s / SUB, sub = s % SUB;
    int kidx = sub * 32 + kk;
    int kw = kidx >> CPLOG;
    int ci = kidx & ((1 << CPLOG) - 1);
    float v = (kw < 5 && ci < CIN) ? w[((size_t)(co * CIN + ci) * 5 + kh) * 5 + kw] : 0.f;
    wT[idx] = f2bf(v);
}

// ------------------------------------------- implicit-GEMM MFMA conv --------
// A-fragments loaded DIRECTLY from padded NHWC global (no LDS, no barrier dep).
// B staged in LDS in chunks of CH steps; 2 barriers per chunk (not per step).
template <int CP, int COUT, int HP, int LOG_OHW, int LOG_OW, int SUB, int NCO, int CH>
__global__ __launch_bounds__(256) void conv_mfma(const unsigned short* __restrict__ inP,
                                                 const unsigned short* __restrict__ wT,
                                                 float* __restrict__ outX) {
    constexpr int NSTEP = 5 * SUB;
    constexpr int NCHUNK = NSTEP / CH;
    static_assert(NSTEP % CH == 0, "CH must divide NSTEP");
    __shared__ short Bs[CH][64][40];
    int tid = threadIdx.x;
    int bm = blockIdx.x / NCO;
    int bco = blockIdx.x % NCO;
    int wave = tid >> 6, lane = tid & 63, q = lane >> 4, l16 = lane & 15;

    // per-lane A fragment base: row m, k-offset q*8
    int m = bm * 64 + wave * 16 + l16;
    int b = m >> LOG_OHW;
    int ohw = m & ((1 << LOG_OHW) - 1);
    int oh = ohw >> LOG_OW, ow = ohw & ((1 << LOG_OW) - 1);
    const short* aBase = (const short*)inP +
        ((size_t)((b * HP + 2 * oh) * HP + 2 * ow)) * CP + q * 8;

    // cooperative B staging addresses
    int r = tid >> 2, cc = tid & 3;
    const short* bg = (const short*)wT + (size_t)(bco * 64 + r) * 32 + cc * 8;

    floatx4 acc[4];
#pragma unroll
    for (int nt = 0; nt < 4; ++nt) acc[nt] = (floatx4){0.f, 0.f, 0.f, 0.f};

    short8 nb[CH];
#pragma unroll
    for (int s = 0; s < CH; ++s) nb[s] = *(const short8*)(bg + (size_t)s * COUT * 32);
#pragma unroll
    for (int s = 0; s < CH; ++s) *(short8*)&Bs[s][r][cc * 8] = nb[s];
    __syncthreads();

    for (int chunk = 0; chunk < NCHUNK; ++chunk) {
        bool has_next = (chunk + 1 < NCHUNK);
        if (has_next) {
#pragma unroll
            for (int s = 0; s < CH; ++s)
                nb[s] = *(const short8*)(bg + (size_t)((chunk + 1) * CH + s) * COUT * 32);
        }
#pragma unroll
        for (int s = 0; s < CH; ++s) {
            int step = chunk * CH + s;
            int kh = step / SUB;
            int sub = step - kh * SUB;
            short8 af = *(const short8*)(aBase + (size_t)(kh * HP) * CP + sub * 32);
#pragma unroll
            for (int nt = 0; nt < 4; ++nt) {
                short8 bf = *(const short8*)&Bs[s][nt * 16 + l16][q * 8];
                acc[nt] = __builtin_amdgcn_mfma_f32_16x16x32_bf16(af, bf, acc[nt], 0, 0, 0);
            }
        }
        if (has_next) {
            __syncthreads();
#pragma unroll
            for (int s = 0; s < CH; ++s) *(short8*)&Bs[s][r][cc * 8] = nb[s];
            __syncthreads();
        }
    }
#pragma unroll
    for (int nt = 0; nt < 4; ++nt) {
#pragma unroll
        for (int rg = 0; rg < 4; ++rg) {
            int mg = bm * 64 + wave * 16 + q * 4 + rg;
            int co = bco * 64 + nt * 16 + l16;
            outX[(size_t)mg * COUT + co] = acc[nt][rg];
        }
    }
}

// --------------------------------------------------- conv4 split-K GEMM -----
// A: bf16 [64][16384] direct per-lane fragment loads; B: w4 fp32 cast->LDS,
// chunked CH=4 steps per barrier pair.
__global__ __launch_bounds__(256) void conv4_mfma(const unsigned short* __restrict__ A,
                                                  const float* __restrict__ w4,
                                                  float* __restrict__ h4) {
    constexpr int CH = 4, NCHUNK = 8;
    __shared__ short Bs[CH][64][40];
    int tid = threadIdx.x;
    int bco = blockIdx.x & 15;
    int ks = blockIdx.x >> 4;
    int wave = tid >> 6, lane = tid & 63, q = lane >> 4, l16 = lane & 15;
    const short* aBase = (const short*)A + (size_t)(wave * 16 + l16) * 16384 + ks * 1024 + q * 8;
    int r = tid >> 2, cc = tid & 3;
    const float* bg = w4 + (size_t)(bco * 64 + r) * 16384 + ks * 1024 + cc * 8;

    floatx4 acc[4];
#pragma unroll
    for (int nt = 0; nt < 4; ++nt) acc[nt] = (floatx4){0.f, 0.f, 0.f, 0.f};

    short8 nb[CH];
#pragma unroll
    for (int s = 0; s < CH; ++s) {
        float4 b0 = *(const float4*)(bg + s * 32);
        float4 b1 = *(const float4*)(bg + s * 32 + 4);
        nb[s][0] = (short)f2bf(b0.x); nb[s][1] = (short)f2bf(b0.y);
        nb[s][2] = (short)f2bf(b0.z); nb[s][3] = (short)f2bf(b0.w);
        nb[s][4] = (short)f2bf(b1.x); nb[s][5] = (short)f2bf(b1.y);
        nb[s][6] = (short)f2bf(b1.z); nb[s][7] = (short)f2bf(b1.w);
    }
#pragma unroll
    for (int s = 0; s < CH; ++s) *(short8*)&Bs[s][r][cc * 8] = nb[s];
    __syncthreads();

    for (int chunk = 0; chunk < NCHUNK; ++chunk) {
        bool has_next = (chunk + 1 < NCHUNK);
        if (has_next) {
#pragma unroll
            for (int s = 0; s < CH; ++s) {
                int step = (chunk + 1) * CH + s;
                float4 b0 = *(const float4*)(bg + step * 32);
                float4 b1 = *(const float4*)(bg + step * 32 + 4);
                nb[s][0] = (short)f2bf(b0.x); nb[s][1] = (short)f2bf(b0.y);
                nb[s][2] = (short)f2bf(b0.z); nb[s][3] = (short)f2bf(b0.w);
                nb[s][4] = (short)f2bf(b1.x); nb[s][5] = (short)f2bf(b1.y);
                nb[s][6] = (short)f2bf(b1.z); nb[s][7] = (short)f2bf(b1.w);
            }
        }
#pragma unroll
        for (int s = 0; s < CH; ++s) {
            int step = chunk * CH + s;
            short8 af = *(const short8*)(aBase + step * 32);
#pragma unroll
            for (int nt = 0; nt < 4; ++nt) {
                short8 bf = *(const short8*)&Bs[s][nt * 16 + l16][q * 8];
                acc[nt] = __builtin_amdgcn_mfma_f32_16x16x32_bf16(af, bf, acc[nt], 0, 0, 0);
            }
        }
        if (has_next) {
            __syncthreads();
#pragma unroll
            for (int s = 0; s < CH; ++s) *(short8*)&Bs[s][r][cc * 8] = nb[s];
            __syncthreads();
        }
    }
#pragma unroll
    for (int nt = 0; nt < 4; ++nt) {
#pragma unroll
        for (int rg = 0; rg < 4; ++rg) {
            int mg = wave * 16 + q * 4 + rg;
            int co = bco * 64 + nt * 16 + l16;
            atomicAdd(&h4[(size_t)mg * 1024 + co], acc[nt][rg]);
        }
    }
}

// ----------------------------------------------------------- batch stats ----
__global__ __launch_bounds__(256) void stats_part(const float* __restrict__ X,
                                                  float* __restrict__ acc,
                                                  int CO, int R, int RPB, int CGLOG) {
    int tid = threadIdx.x;
    int cg = blockIdx.x & ((1 << CGLOG) - 1);
    int rb = blockIdx.x >> CGLOG;
    int c = (cg << 6) + (tid & 63);
    int w = tid >> 6;
    float s = 0.f, s2 = 0.f;
    int rend = min(R, (rb + 1) * RPB);
    for (int r = rb * RPB + w; r < rend; r += 4) {
        float v = X[(size_t)r * CO + c];
        s += v; s2 += v * v;
    }
    __shared__ float ls[4][64], ls2[4][64];
    ls[w][tid & 63] = s; ls2[w][tid & 63] = s2;
    __syncthreads();
    if (tid < 64) {
        float ts = ls[0][tid] + ls[1][tid] + ls[2][tid] + ls[3][tid];
        float ts2 = ls2[0][tid] + ls2[1][tid] + ls2[2][tid] + ls2[3][tid];
        int cc = (cg << 6) + tid;
        atomicAdd(&acc[cc], ts);
        atomicAdd(&acc[CO + cc], ts2);
    }
}

__global__ __launch_bounds__(256) void bn_finalize(const float* __restrict__ acc,
                                                   const float* __restrict__ g,
                                                   const float* __restrict__ bb,
                                                   float* __restrict__ st,
                                                   int CO, float invN) {
    int c = blockIdx.x * 256 + threadIdx.x;
    if (c >= CO) return;
    float mean = acc[c] * invN;
    float var = fmaxf(acc[CO + c] * invN - mean * mean, 0.f);
    float sc = g[c] * rsqrtf(var + EPS);
    st[c] = sc;
    st[CO + c] = bb[c] - mean * sc;
}

// ---------------------------------- BN + lrelu + pad + bf16 (NHWC->NHWC) ----
__global__ __launch_bounds__(256) void bnpad_kernel(const float* __restrict__ X,
                                                    const float* __restrict__ st,
                                                    unsigned short* __restrict__ out,
                                                    int CO_LOG, int OH, int OHP, int total) {
    int idx = blockIdx.x * 256 + threadIdx.x;
    if (idx >= total) return;
    int c = idx & ((1 << CO_LOG) - 1);
    int t = idx >> CO_LOG;
    int x = t % OHP; t /= OHP;
    int y = t % OHP; int b = t / OHP;
    unsigned short v = 0;
    if (y >= 2 && y < OH + 2 && x >= 2 && x < OH + 2) {
        float f = X[(((size_t)(b * OH + (y - 2)) * OH + (x - 2)) << CO_LOG) + c];
        f = f * st[c] + st[(1 << CO_LOG) + c];
        f = f >= 0.f ? f : NEG * f;
        v = f2bf(f);
    }
    out[idx] = v;
}

// ------------------------- BN + lrelu + bf16, NHWC -> NCHW (conv4 input) ----
__global__ __launch_bounds__(256) void bn_nchw_kernel(const float* __restrict__ X,
                                                      const float* __restrict__ st,
                                                      unsigned short* __restrict__ out,
                                                      int total) {
    int idx = blockIdx.x * 256 + threadIdx.x;
    if (idx >= total) return;
    int hw = idx & 63;
    int ci = (idx >> 6) & 255;
    int b = idx >> 14;
    float f = X[((size_t)(b * 64 + hw)) * 256 + ci];
    f = f * st[ci] + st[256 + ci];
    f = f >= 0.f ? f : NEG * f;
    out[idx] = f2bf(f);
}

// ------------------------------------------------- conv5 (fused BN4) --------
__global__ __launch_bounds__(256) void conv5_kernel(const float* __restrict__ X,
                                                    const float* __restrict__ st,
                                                    const float* __restrict__ w5,
                                                    const float* __restrict__ b5,
                                                    float* __restrict__ out) {
    int b = blockIdx.x, tid = threadIdx.x;
    float s = 0.f;
    for (int c = tid; c < 1024; c += 256) {
        float f = X[(size_t)b * 1024 + c] * st[c] + st[1024 + c];
        f = f >= 0.f ? f : NEG * f;
        s = fmaf(f, w5[c], s);
    }
#pragma unroll
    for (int off = 32; off > 0; off >>= 1) s += __shfl_down(s, off);
    __shared__ float ls[4];
    if ((tid & 63) == 0) ls[tid >> 6] = s;
    __syncthreads();
    if (tid == 0) out[b] = ls[0] + ls[1] + ls[2] + ls[3] + b5[0];
}

// ----------------------------------------------------------------- launch ---
extern "C" void kernel_launch(void* const* d_in, const int* in_sizes, int n_in,
                              void* d_out, int out_size, void* d_ws, size_t ws_size,
                              hipStream_t stream) {
    (void)in_sizes; (void)n_in; (void)out_size; (void)ws_size;
    const float* input_data = (const float*)d_in[0];
    const float* w1 = (const float*)d_in[2];
    const float* g1 = (const float*)d_in[3];
    const float* b1 = (const float*)d_in[4];
    const float* w2 = (const float*)d_in[5];
    const float* g2 = (const float*)d_in[6];
    const float* b2 = (const float*)d_in[7];
    const float* w3 = (const float*)d_in[8];
    const float* g3 = (const float*)d_in[9];
    const float* b3 = (const float*)d_in[10];
    const float* w4 = (const float*)d_in[11];
    const float* g4 = (const float*)d_in[12];
    const float* b4 = (const float*)d_in[13];
    const float* w5 = (const float*)d_in[14];
    const float* b5 = (const float*)d_in[15];

    char* ws = (char*)d_ws;
    float* regA = (float*)ws;               // 16.8 MB: conv1out / conv3out
    char* wsB = ws + 16777216;              // 10.7 MB: pad1 / pad2
    char* wsC = wsB + 10616832;             // 9.5 MB: rendered / conv2out / a4
    char* wsD = wsC + 9469952;
    float* h4 = (float*)wsD;                                    // 262144
    float* stacc = (float*)(wsD + 262144);                      // 8192
    float* st = (float*)(wsD + 270336);                         // 8192
    unsigned short* wT1 = (unsigned short*)(wsD + 278528);      // 61440
    unsigned short* wT2 = (unsigned short*)(wsD + 339968);      // 409600
    unsigned short* wT3 = (unsigned short*)(wsD + 749568);      // 1638400

    unsigned short* rendered = (unsigned short*)wsC;
    float* conv1out = regA;
    unsigned short* pad1 = (unsigned short*)wsB;
    float* conv2out = (float*)wsC;
    unsigned short* pad2 = (unsigned short*)wsB;
    float* conv3out = regA;
    unsigned short* a4 = (unsigned short*)wsC;

    wtrans_kernel<<<120, 256, 0, stream>>>(w1, wT1, 14, 4, 3, 6, 30720);
    wtrans_kernel<<<800, 256, 0, stream>>>(w2, wT2, 64, 6, 10, 7, 204800);
    wtrans_kernel<<<3200, 256, 0, stream>>>(w3, wT3, 128, 7, 20, 8, 819200);

    hipMemsetAsync(rendered, 0, 9469952, stream);
    hipMemsetAsync(h4, 0, 262144, stream);

    render_kernel<<<1024, 256, 0, stream>>>(input_data, rendered);

    // conv1: [64,16p,68,68] -> [65536,64]   (NSTEP=15, CH=5)
    conv_mfma<16, 64, 68, 10, 5, 3, 1, 5><<<1024, 256, 0, stream>>>(rendered, wT1, conv1out);
    hipMemsetAsync(stacc, 0, 8192, stream);
    stats_part<<<128, 256, 0, stream>>>(conv1out, stacc, 64, 65536, 512, 0);
    bn_finalize<<<1, 256, 0, stream>>>(stacc, g1, b1, st, 64, 1.f / 65536.f);
    bnpad_kernel<<<20736, 256, 0, stream>>>(conv1out, st, pad1, 6, 32, 36, 5308416);

    // conv2: [64,64,36,36p] -> [16384,128]  (NSTEP=50, CH=10)
    conv_mfma<64, 128, 36, 8, 4, 10, 2, 10><<<512, 256, 0, stream>>>(pad1, wT2, conv2out);
    hipMemsetAsync(stacc, 0, 8192, stream);
    stats_part<<<256, 256, 0, stream>>>(conv2out, stacc, 128, 16384, 128, 1);
    bn_finalize<<<1, 256, 0, stream>>>(stacc, g2, b2, st, 128, 1.f / 16384.f);
    bnpad_kernel<<<12800, 256, 0, stream>>>(conv2out, st, pad2, 7, 16, 20, 3276800);

    // conv3: [64,128,20,20p] -> [4096,256]  (NSTEP=100, CH=10)
    conv_mfma<128, 256, 20, 6, 3, 20, 4, 10><<<256, 256, 0, stream>>>(pad2, wT3, conv3out);
    hipMemsetAsync(stacc, 0, 8192, stream);
    stats_part<<<512, 256, 0, stream>>>(conv3out, stacc, 256, 4096, 32, 2);
    bn_finalize<<<1, 256, 0, stream>>>(stacc, g3, b3, st, 256, 1.f / 4096.f);
    bn_nchw_kernel<<<4096, 256, 0, stream>>>(conv3out, st, a4, 1048576);

    // conv4: [64,16384] x [1024,16384]^T -> [64,1024], split-K=16
    conv4_mfma<<<256, 256, 0, stream>>>(a4, w4, h4);
    hipMemsetAsync(stacc, 0, 8192, stream);
    stats_part<<<16, 256, 0, stream>>>(h4, stacc, 1024, 64, 64, 4);
    bn_finalize<<<4, 256, 0, stream>>>(stacc, g4, b4, st, 1024, 1.f / 64.f);

    conv5_kernel<<<64, 256, 0, stream>>>(h4, st, w5, b5, (float*)d_out);
}

// Round 5
// 304.396 us; speedup vs baseline: 3.9408x; 1.0243x over previous
//
#include <hip/hip_runtime.h>
#include <hip/hip_bf16.h>

#define NEG 0.01f
#define EPS 1e-5f

typedef __attribute__((ext_vector_type(8))) short short8;
typedef __attribute__((ext_vector_type(4))) float floatx4;

__device__ inline unsigned short f2bf(float f) {
    __hip_bfloat16 h = __float2bfloat16(f);
    union { __hip_bfloat16 h; unsigned short u; } cv; cv.h = h;
    return cv.u;
}

// async 16B global->LDS DMA: LDS dest = uniform base + lane*16
__device__ inline void dma16(const unsigned short* g, unsigned short* l) {
    __builtin_amdgcn_global_load_lds(
        (const __attribute__((address_space(1))) void*)g,
        (__attribute__((address_space(3))) void*)l, 16, 0, 0);
}

// ---------------------------------------------------------------- render ----
// Writes padded NHWC bf16 [64][68][68][16] INCLUDING zero borders + ch14/15.
__global__ __launch_bounds__(256) void render_kernel(const float* __restrict__ in,
                                                     unsigned short* __restrict__ out) {
    int b = blockIdx.x >> 4;
    int chunk = blockIdx.x & 15;
    __shared__ float r0[46], r1[46], r2[46], r3[46];
    __shared__ float cls_s[46 * 14];
    int tid = threadIdx.x;
    if (tid < 46) {
        const float* p = in + ((size_t)b * 46 + tid) * 18 + 14;
        float x = p[0] * 64.f, y = p[1] * 64.f, w = p[2] * 64.f, h = p[3] * 64.f;
        r0[tid] = x - 0.5f * w; r1[tid] = x + 0.5f * w;
        r2[tid] = y - 0.5f * h; r3[tid] = y + 0.5f * h;
    }
    for (int idx = tid; idx < 46 * 14; idx += 256) {
        int n = idx / 14, c = idx % 14;
        cls_s[idx] = in[((size_t)b * 46 + n) * 18 + c];
    }
    __syncthreads();
    // border zeroing: 528 border px, 33 per block
    if (tid < 33) {
        int j = chunk * 33 + tid;
        if (j < 528) {
            int y, x;
            if (j < 136) { y = j / 68; x = j - y * 68; }
            else if (j < 272) { int t = j - 136; int yy = t / 68; y = 66 + yy; x = t - yy * 68; }
            else { int t = j - 272; y = 2 + (t >> 2); int k = t & 3; x = (k < 2) ? k : 64 + k; }
            size_t zb = (((size_t)b * 68 + y) * 68 + x) * 16;
            short8 z; 
#pragma unroll
            for (int i = 0; i < 8; ++i) z[i] = 0;
            *(short8*)(out + zb) = z;
            *(short8*)(out + zb + 8) = z;
        }
    }
    int pix = chunk * 256 + tid;
    float cx = (float)(pix & 63);
    float cy = (float)(pix >> 6);
    float acc[14];
#pragma unroll
    for (int c = 0; c < 14; ++c) acc[c] = 0.f;
    for (int n = 0; n < 46; ++n) {
        float x0 = r0[n], x1 = r1[n], y0 = r2[n], y1 = r3[n];
        float by = fminf(fmaxf(cy - y0, 0.f), 1.f) * fminf(fmaxf(y1 - cy, 0.f), 1.f);
        float bx = fminf(fmaxf(cx - x0, 0.f), 1.f) * fminf(fmaxf(x1 - cx, 0.f), 1.f);
        float kx0 = fmaxf(1.f - fabsf(cx - x0), 0.f);
        float kx1 = fmaxf(1.f - fabsf(cx - x1), 0.f);
        float ky0 = fmaxf(1.f - fabsf(cy - y0), 0.f);
        float ky1 = fmaxf(1.f - fabsf(cy - y1), 0.f);
        float r = fmaxf(fmaxf(kx0 * by, kx1 * by), fmaxf(ky0 * bx, ky1 * bx));
        if (r > 0.f) {
#pragma unroll
            for (int c = 0; c < 14; ++c) acc[c] = fmaf(cls_s[n * 14 + c], r, acc[c]);
        }
    }
    size_t obase = (((size_t)b * 68 + ((pix >> 6) + 2)) * 68 + ((pix & 63) + 2)) * 16;
    short8 v0, v1;
#pragma unroll
    for (int i = 0; i < 8; ++i) v0[i] = (short)f2bf(acc[i]);
#pragma unroll
    for (int i = 0; i < 6; ++i) v1[i] = (short)f2bf(acc[8 + i]);
    v1[6] = 0; v1[7] = 0;
    *(short8*)(out + obase) = v0;
    *(short8*)(out + obase + 8) = v1;
}

// ------------------------------------------- merged weight transform --------
__global__ __launch_bounds__(256) void wtrans_all(const float* __restrict__ w1,
                                                  const float* __restrict__ w2,
                                                  const float* __restrict__ w3,
                                                  unsigned short* __restrict__ wT1,
                                                  unsigned short* __restrict__ wT2,
                                                  unsigned short* __restrict__ wT3) {
    int idx = blockIdx.x * 256 + threadIdx.x;
    const float* w; unsigned short* wT; int CIN, CPLOG, SUB, COLOG;
    if (idx < 30720) { w = w1; wT = wT1; CIN = 14; CPLOG = 4; SUB = 3; COLOG = 6; }
    else if (idx < 235520) { idx -= 30720; w = w2; wT = wT2; CIN = 64; CPLOG = 6; SUB = 10; COLOG = 7; }
    else if (idx < 1054720) { idx -= 235520; w = w3; wT = wT3; CIN = 128; CPLOG = 7; SUB = 20; COLOG = 8; }
    else return;
    int kk = idx & 31;
    int co = (idx >> 5) & ((1 << COLOG) - 1);
    int s = idx >> (5 + COLOG);
    int kh = s / SUB, sub = s - kh * SUB;
    int kidx = sub * 32 + kk;
    int kw = kidx >> CPLOG;
    int ci = kidx & ((1 << CPLOG) - 1);
    float v = (kw < 5 && ci < CIN) ? w[((size_t)(co * CIN + ci) * 5 + kh) * 5 + kw] : 0.f;
    wT[idx] = f2bf(v);
}

// ------------------------------------------- implicit-GEMM MFMA conv --------
// Single-wave blocks (64 thr). Wave tile = 64 px x (NT*16) co: 4*NT MFMA/step
// from 4 direct-global A loads + NT LDS B reads. B staged via global_load_lds
// DMA, double-buffered per CH-step chunk -> only s_waitcnt per chunk.
// Fused BN stats (sum/sumsq per channel) via shfl + atomics.
template <int CP, int COUT, int HP, int LOG_OHW, int LOG_OW, int SUB, int NCO, int NT, int CH>
__global__ __launch_bounds__(64) void conv_mfma(const unsigned short* __restrict__ inP,
                                                const unsigned short* __restrict__ wT,
                                                float* __restrict__ outX,
                                                float* __restrict__ stacc) {
    constexpr int NSTEP = 5 * SUB;
    constexpr int NCHUNK = NSTEP / CH;
    static_assert(NSTEP % CH == 0, "CH must divide NSTEP");
    __shared__ short Bs[2][CH][NT * 16][32];
    int lane = threadIdx.x;
    int q = lane >> 4, l16 = lane & 15;
    int bm = blockIdx.x / NCO, bco = blockIdx.x % NCO;

    const short* aB[4];
#pragma unroll
    for (int f = 0; f < 4; ++f) {
        int m = bm * 64 + f * 16 + l16;
        int b = m >> LOG_OHW;
        int ohw = m & ((1 << LOG_OHW) - 1);
        int oh = ohw >> LOG_OW, ow = ohw & ((1 << LOG_OW) - 1);
        aB[f] = (const short*)inP + ((size_t)((b * HP + 2 * oh) * HP + 2 * ow)) * CP + q * 8;
    }
    // B source: step-row is contiguous [NT*16 co][32 k]; lane covers 16B at lane*16
    const unsigned short* bg = wT + ((size_t)bco * NT * 16) * 32 + lane * 8;

    floatx4 acc[4][NT];
#pragma unroll
    for (int f = 0; f < 4; ++f)
#pragma unroll
        for (int nt = 0; nt < NT; ++nt) acc[f][nt] = (floatx4){0.f, 0.f, 0.f, 0.f};

    // stage chunk 0 into buffer 0
#pragma unroll
    for (int s = 0; s < CH; ++s)
#pragma unroll
        for (int k = 0; k < NT; ++k)
            dma16(bg + (size_t)s * COUT * 32 + k * 512,
                  (unsigned short*)&Bs[0][s][0][0] + k * 512);
    asm volatile("s_waitcnt vmcnt(0)" ::: "memory");
    __syncthreads();

    for (int chunk = 0; chunk < NCHUNK; ++chunk) {
        int cur = chunk & 1;
        if (chunk + 1 < NCHUNK) {
#pragma unroll
            for (int s = 0; s < CH; ++s)
#pragma unroll
                for (int k = 0; k < NT; ++k)
                    dma16(bg + (size_t)((chunk + 1) * CH + s) * COUT * 32 + k * 512,
                          (unsigned short*)&Bs[cur ^ 1][s][0][0] + k * 512);
        }
#pragma unroll
        for (int s = 0; s < CH; ++s) {
            int step = chunk * CH + s;
            int kh = step / SUB;
            int sub = step - kh * SUB;
            short8 af[4];
#pragma unroll
            for (int f = 0; f < 4; ++f)
                af[f] = *(const short8*)(aB[f] + (size_t)(kh * HP) * CP + sub * 32);
#pragma unroll
            for (int nt = 0; nt < NT; ++nt) {
                short8 bf = *(const short8*)&Bs[cur][s][nt * 16 + l16][q * 8];
#pragma unroll
                for (int f = 0; f < 4; ++f)
                    acc[f][nt] = __builtin_amdgcn_mfma_f32_16x16x32_bf16(af[f], bf, acc[f][nt], 0, 0, 0);
            }
        }
        asm volatile("s_waitcnt vmcnt(0)" ::: "memory");
        __syncthreads();
    }
    // output
#pragma unroll
    for (int f = 0; f < 4; ++f)
#pragma unroll
        for (int nt = 0; nt < NT; ++nt)
#pragma unroll
            for (int rg = 0; rg < 4; ++rg) {
                int mg = bm * 64 + f * 16 + q * 4 + rg;
                int co = bco * NT * 16 + nt * 16 + l16;
                outX[(size_t)mg * COUT + co] = acc[f][nt][rg];
            }
    // fused BN stats
#pragma unroll
    for (int nt = 0; nt < NT; ++nt) {
        float s = 0.f, s2 = 0.f;
#pragma unroll
        for (int f = 0; f < 4; ++f)
#pragma unroll
            for (int rg = 0; rg < 4; ++rg) {
                float v = acc[f][nt][rg];
                s += v; s2 = fmaf(v, v, s2);
            }
        s += __shfl_xor(s, 16); s += __shfl_xor(s, 32);
        s2 += __shfl_xor(s2, 16); s2 += __shfl_xor(s2, 32);
        if (q == 0) {
            int co = bco * NT * 16 + nt * 16 + l16;
            atomicAdd(&stacc[co], s);
            atomicAdd(&stacc[COUT + co], s2);
        }
    }
}

// --------------------------------------------------- conv4 split-K GEMM -----
__global__ __launch_bounds__(256) void conv4_mfma(const unsigned short* __restrict__ A,
                                                  const float* __restrict__ w4,
                                                  float* __restrict__ h4) {
    constexpr int CH = 4, NCHUNK = 8;
    __shared__ short Bs[CH][64][40];
    int tid = threadIdx.x;
    int bco = blockIdx.x & 15;
    int ks = blockIdx.x >> 4;
    int wave = tid >> 6, lane = tid & 63, q = lane >> 4, l16 = lane & 15;
    const short* aBase = (const short*)A + (size_t)(wave * 16 + l16) * 16384 + ks * 1024 + q * 8;
    int r = tid >> 2, cc = tid & 3;
    const float* bg = w4 + (size_t)(bco * 64 + r) * 16384 + ks * 1024 + cc * 8;

    floatx4 acc[4];
#pragma unroll
    for (int nt = 0; nt < 4; ++nt) acc[nt] = (floatx4){0.f, 0.f, 0.f, 0.f};

    short8 nb[CH];
#pragma unroll
    for (int s = 0; s < CH; ++s) {
        float4 b0 = *(const float4*)(bg + s * 32);
        float4 b1 = *(const float4*)(bg + s * 32 + 4);
        nb[s][0] = (short)f2bf(b0.x); nb[s][1] = (short)f2bf(b0.y);
        nb[s][2] = (short)f2bf(b0.z); nb[s][3] = (short)f2bf(b0.w);
        nb[s][4] = (short)f2bf(b1.x); nb[s][5] = (short)f2bf(b1.y);
        nb[s][6] = (short)f2bf(b1.z); nb[s][7] = (short)f2bf(b1.w);
    }
#pragma unroll
    for (int s = 0; s < CH; ++s) *(short8*)&Bs[s][r][cc * 8] = nb[s];
    __syncthreads();

    for (int chunk = 0; chunk < NCHUNK; ++chunk) {
        bool has_next = (chunk + 1 < NCHUNK);
        if (has_next) {
#pragma unroll
            for (int s = 0; s < CH; ++s) {
                int step = (chunk + 1) * CH + s;
                float4 b0 = *(const float4*)(bg + step * 32);
                float4 b1 = *(const float4*)(bg + step * 32 + 4);
                nb[s][0] = (short)f2bf(b0.x); nb[s][1] = (short)f2bf(b0.y);
                nb[s][2] = (short)f2bf(b0.z); nb[s][3] = (short)f2bf(b0.w);
                nb[s][4] = (short)f2bf(b1.x); nb[s][5] = (short)f2bf(b1.y);
                nb[s][6] = (short)f2bf(b1.z); nb[s][7] = (short)f2bf(b1.w);
            }
        }
#pragma unroll
        for (int s = 0; s < CH; ++s) {
            int step = chunk * CH + s;
            short8 af = *(const short8*)(aBase + step * 32);
#pragma unroll
            for (int nt = 0; nt < 4; ++nt) {
                short8 bf = *(const short8*)&Bs[s][nt * 16 + l16][q * 8];
                acc[nt] = __builtin_amdgcn_mfma_f32_16x16x32_bf16(af, bf, acc[nt], 0, 0, 0);
            }
        }
        if (has_next) {
            __syncthreads();
#pragma unroll
            for (int s = 0; s < CH; ++s) *(short8*)&Bs[s][r][cc * 8] = nb[s];
            __syncthreads();
        }
    }
#pragma unroll
    for (int nt = 0; nt < 4; ++nt) {
#pragma unroll
        for (int rg = 0; rg < 4; ++rg) {
            int mg = wave * 16 + q * 4 + rg;
            int co = bco * 64 + nt * 16 + l16;
            atomicAdd(&h4[(size_t)mg * 1024 + co], acc[nt][rg]);
        }
    }
}

// ----------------------------------------------------------- batch stats ----
__global__ __launch_bounds__(256) void stats_part(const float* __restrict__ X,
                                                  float* __restrict__ acc,
                                                  int CO, int R, int RPB, int CGLOG) {
    int tid = threadIdx.x;
    int cg = blockIdx.x & ((1 << CGLOG) - 1);
    int rb = blockIdx.x >> CGLOG;
    int c = (cg << 6) + (tid & 63);
    int w = tid >> 6;
    float s = 0.f, s2 = 0.f;
    int rend = min(R, (rb + 1) * RPB);
    for (int r = rb * RPB + w; r < rend; r += 4) {
        float v = X[(size_t)r * CO + c];
        s += v; s2 += v * v;
    }
    __shared__ float ls[4][64], ls2[4][64];
    ls[w][tid & 63] = s; ls2[w][tid & 63] = s2;
    __syncthreads();
    if (tid < 64) {
        float ts = ls[0][tid] + ls[1][tid] + ls[2][tid] + ls[3][tid];
        float ts2 = ls2[0][tid] + ls2[1][tid] + ls2[2][tid] + ls2[3][tid];
        int cc = (cg << 6) + tid;
        atomicAdd(&acc[cc], ts);
        atomicAdd(&acc[CO + cc], ts2);
    }
}

// ------------------- BN(inline finalize) + lrelu + pad + bf16 (NHWC) --------
__global__ __launch_bounds__(256) void bnpad_kernel(const float* __restrict__ X,
                                                    const float* __restrict__ stacc,
                                                    const float* __restrict__ g,
                                                    const float* __restrict__ bb,
                                                    unsigned short* __restrict__ out,
                                                    int CO_LOG, int OH, int OHP,
                                                    float invN, int total) {
    int idx = blockIdx.x * 256 + threadIdx.x;
    if (idx >= total) return;
    int CO = 1 << CO_LOG;
    int c = idx & (CO - 1);
    float mean = stacc[c] * invN;
    float var = fmaxf(stacc[CO + c] * invN - mean * mean, 0.f);
    float sc = g[c] * rsqrtf(var + EPS);
    float sh = bb[c] - mean * sc;
    int t = idx >> CO_LOG;
    int x = t % OHP; t /= OHP;
    int y = t % OHP; int b = t / OHP;
    unsigned short v = 0;
    if (y >= 2 && y < OH + 2 && x >= 2 && x < OH + 2) {
        float f = X[(((size_t)(b * OH + (y - 2)) * OH + (x - 2)) << CO_LOG) + c];
        f = f * sc + sh;
        f = f >= 0.f ? f : NEG * f;
        v = f2bf(f);
    }
    out[idx] = v;
}

// -------- BN(inline finalize) + lrelu + bf16, NHWC -> NCHW (conv4 input) ----
__global__ __launch_bounds__(256) void bn_nchw_kernel(const float* __restrict__ X,
                                                      const float* __restrict__ stacc,
                                                      const float* __restrict__ g,
                                                      const float* __restrict__ bb,
                                                      unsigned short* __restrict__ out,
                                                      int total) {
    int idx = blockIdx.x * 256 + threadIdx.x;
    if (idx >= total) return;
    int hw = idx & 63;
    int ci = (idx >> 6) & 255;
    int b = idx >> 14;
    float mean = stacc[ci] * (1.f / 4096.f);
    float var = fmaxf(stacc[256 + ci] * (1.f / 4096.f) - mean * mean, 0.f);
    float sc = g[ci] * rsqrtf(var + EPS);
    float sh = bb[ci] - mean * sc;
    float f = X[((size_t)(b * 64 + hw)) * 256 + ci] * sc + sh;
    f = f >= 0.f ? f : NEG * f;
    out[idx] = f2bf(f);
}

// -------------------------------------- conv5 (inline BN4 finalize) ---------
__global__ __launch_bounds__(256) void conv5_kernel(const float* __restrict__ X,
                                                    const float* __restrict__ stacc,
                                                    const float* __restrict__ g,
                                                    const float* __restrict__ bb,
                                                    const float* __restrict__ w5,
                                                    const float* __restrict__ b5,
                                                    float* __restrict__ out) {
    int b = blockIdx.x, tid = threadIdx.x;
    float s = 0.f;
    for (int c = tid; c < 1024; c += 256) {
        float mean = stacc[c] * (1.f / 64.f);
        float var = fmaxf(stacc[1024 + c] * (1.f / 64.f) - mean * mean, 0.f);
        float sc = g[c] * rsqrtf(var + EPS);
        float sh = bb[c] - mean * sc;
        float f = X[(size_t)b * 1024 + c] * sc + sh;
        f = f >= 0.f ? f : NEG * f;
        s = fmaf(f, w5[c], s);
    }
#pragma unroll
    for (int off = 32; off > 0; off >>= 1) s += __shfl_down(s, off);
    __shared__ float ls[4];
    if ((tid & 63) == 0) ls[tid >> 6] = s;
    __syncthreads();
    if (tid == 0) out[b] = ls[0] + ls[1] + ls[2] + ls[3] + b5[0];
}

// ----------------------------------------------------------------- launch ---
extern "C" void kernel_launch(void* const* d_in, const int* in_sizes, int n_in,
                              void* d_out, int out_size, void* d_ws, size_t ws_size,
                              hipStream_t stream) {
    (void)in_sizes; (void)n_in; (void)out_size; (void)ws_size;
    const float* input_data = (const float*)d_in[0];
    const float* w1 = (const float*)d_in[2];
    const float* g1 = (const float*)d_in[3];
    const float* b1 = (const float*)d_in[4];
    const float* w2 = (const float*)d_in[5];
    const float* g2 = (const float*)d_in[6];
    const float* b2 = (const float*)d_in[7];
    const float* w3 = (const float*)d_in[8];
    const float* g3 = (const float*)d_in[9];
    const float* b3 = (const float*)d_in[10];
    const float* w4 = (const float*)d_in[11];
    const float* g4 = (const float*)d_in[12];
    const float* b4 = (const float*)d_in[13];
    const float* w5 = (const float*)d_in[14];
    const float* b5 = (const float*)d_in[15];

    char* ws = (char*)d_ws;
    float* regA = (float*)ws;               // 16.8 MB: conv1out / conv3out
    char* wsB = ws + 16777216;              // 10.7 MB: pad1 / pad2
    char* wsC = wsB + 10616832;             // 9.5 MB: rendered / conv2out / a4
    char* wsD = wsC + 9469952;
    float* h4  = (float*)wsD;                               // 262,144 B
    float* st1 = (float*)(wsD + 262144);                    // 512 B  (64*2)
    float* st2 = (float*)(wsD + 262656);                    // 1024 B (128*2)
    float* st3 = (float*)(wsD + 263680);                    // 2048 B (256*2)
    float* st4 = (float*)(wsD + 265728);                    // 8192 B (1024*2)
    unsigned short* wT1 = (unsigned short*)(wsD + 274432);  // 61,440 B
    unsigned short* wT2 = (unsigned short*)(wsD + 335872);  // 409,600 B
    unsigned short* wT3 = (unsigned short*)(wsD + 745472);  // 1,638,400 B

    unsigned short* rendered = (unsigned short*)wsC;
    float* conv1out = regA;
    unsigned short* pad1 = (unsigned short*)wsB;
    float* conv2out = (float*)wsC;
    unsigned short* pad2 = (unsigned short*)wsB;
    float* conv3out = regA;
    unsigned short* a4 = (unsigned short*)wsC;

    // one memset covers h4 + all stat accumulators
    hipMemsetAsync(wsD, 0, 273920, stream);
    wtrans_all<<<4120, 256, 0, stream>>>(w1, w2, w3, wT1, wT2, wT3);
    render_kernel<<<1024, 256, 0, stream>>>(input_data, rendered);

    // conv1: [64,16p,68,68] -> [65536,64]  (NT=4, 1024 single-wave blocks)
    conv_mfma<16, 64, 68, 10, 5, 3, 1, 4, 5><<<1024, 64, 0, stream>>>(rendered, wT1, conv1out, st1);
    bnpad_kernel<<<20736, 256, 0, stream>>>(conv1out, st1, g1, b1, pad1, 6, 32, 36, 1.f / 65536.f, 5308416);

    // conv2: [64,64,36,36p] -> [16384,128]  (NT=2, NCO=4 -> 1024 blocks)
    conv_mfma<64, 128, 36, 8, 4, 10, 4, 2, 5><<<1024, 64, 0, stream>>>(pad1, wT2, conv2out, st2);
    bnpad_kernel<<<12800, 256, 0, stream>>>(conv2out, st2, g2, b2, pad2, 7, 16, 20, 1.f / 16384.f, 3276800);

    // conv3: [64,128,20,20p] -> [4096,256]  (NT=2, NCO=8 -> 512 blocks)
    conv_mfma<128, 256, 20, 6, 3, 20, 8, 2, 5><<<512, 64, 0, stream>>>(pad2, wT3, conv3out, st3);
    bn_nchw_kernel<<<4096, 256, 0, stream>>>(conv3out, st3, g3, b3, a4, 1048576);

    // conv4: [64,16384] x [1024,16384]^T -> [64,1024], split-K=16
    conv4_mfma<<<256, 256, 0, stream>>>(a4, w4, h4);
    stats_part<<<16, 256, 0, stream>>>(h4, st4, 1024, 64, 64, 4);

    // conv5 (inline BN4)
    conv5_kernel<<<64, 256, 0, stream>>>(h4, st4, g4, b4, w5, b5, (float*)d_out);
}

// Round 6
// 278.917 us; speedup vs baseline: 4.3008x; 1.0914x over previous
//
#include <hip/hip_runtime.h>
#include <hip/hip_bf16.h>

#define NEG 0.01f
#define EPS 1e-5f

typedef __attribute__((ext_vector_type(8))) short short8;
typedef __attribute__((ext_vector_type(4))) float floatx4;

__device__ inline unsigned short f2bf(float f) {
    __hip_bfloat16 h = __float2bfloat16(f);
    union { __hip_bfloat16 h; unsigned short u; } cv; cv.h = h;
    return cv.u;
}

// ---------------------------------------------------------------- render ----
// Writes padded NHWC bf16 [64][68][68][16] INCLUDING zero borders + ch14/15.
__global__ __launch_bounds__(256) void render_kernel(const float* __restrict__ in,
                                                     unsigned short* __restrict__ out) {
    int b = blockIdx.x >> 4;
    int chunk = blockIdx.x & 15;
    __shared__ float r0[46], r1[46], r2[46], r3[46];
    __shared__ float cls_s[46 * 14];
    int tid = threadIdx.x;
    if (tid < 46) {
        const float* p = in + ((size_t)b * 46 + tid) * 18 + 14;
        float x = p[0] * 64.f, y = p[1] * 64.f, w = p[2] * 64.f, h = p[3] * 64.f;
        r0[tid] = x - 0.5f * w; r1[tid] = x + 0.5f * w;
        r2[tid] = y - 0.5f * h; r3[tid] = y + 0.5f * h;
    }
    for (int idx = tid; idx < 46 * 14; idx += 256) {
        int n = idx / 14, c = idx % 14;
        cls_s[idx] = in[((size_t)b * 46 + n) * 18 + c];
    }
    __syncthreads();
    // border zeroing: 528 border px, 33 per block
    if (tid < 33) {
        int j = chunk * 33 + tid;
        if (j < 528) {
            int y, x;
            if (j < 136) { y = j / 68; x = j - y * 68; }
            else if (j < 272) { int t = j - 136; int yy = t / 68; y = 66 + yy; x = t - yy * 68; }
            else { int t = j - 272; y = 2 + (t >> 2); int k = t & 3; x = (k < 2) ? k : 64 + k; }
            size_t zb = (((size_t)b * 68 + y) * 68 + x) * 16;
            short8 z;
#pragma unroll
            for (int i = 0; i < 8; ++i) z[i] = 0;
            *(short8*)(out + zb) = z;
            *(short8*)(out + zb + 8) = z;
        }
    }
    int pix = chunk * 256 + tid;
    float cx = (float)(pix & 63);
    float cy = (float)(pix >> 6);
    float acc[14];
#pragma unroll
    for (int c = 0; c < 14; ++c) acc[c] = 0.f;
    for (int n = 0; n < 46; ++n) {
        float x0 = r0[n], x1 = r1[n], y0 = r2[n], y1 = r3[n];
        float by = fminf(fmaxf(cy - y0, 0.f), 1.f) * fminf(fmaxf(y1 - cy, 0.f), 1.f);
        float bx = fminf(fmaxf(cx - x0, 0.f), 1.f) * fminf(fmaxf(x1 - cx, 0.f), 1.f);
        float kx0 = fmaxf(1.f - fabsf(cx - x0), 0.f);
        float kx1 = fmaxf(1.f - fabsf(cx - x1), 0.f);
        float ky0 = fmaxf(1.f - fabsf(cy - y0), 0.f);
        float ky1 = fmaxf(1.f - fabsf(cy - y1), 0.f);
        float r = fmaxf(fmaxf(kx0 * by, kx1 * by), fmaxf(ky0 * bx, ky1 * bx));
        if (r > 0.f) {
#pragma unroll
            for (int c = 0; c < 14; ++c) acc[c] = fmaf(cls_s[n * 14 + c], r, acc[c]);
        }
    }
    size_t obase = (((size_t)b * 68 + ((pix >> 6) + 2)) * 68 + ((pix & 63) + 2)) * 16;
    short8 v0, v1;
#pragma unroll
    for (int i = 0; i < 8; ++i) v0[i] = (short)f2bf(acc[i]);
#pragma unroll
    for (int i = 0; i < 6; ++i) v1[i] = (short)f2bf(acc[8 + i]);
    v1[6] = 0; v1[7] = 0;
    *(short8*)(out + obase) = v0;
    *(short8*)(out + obase + 8) = v1;
}

// ------------------------------------------- merged weight transform --------
__global__ __launch_bounds__(256) void wtrans_all(const float* __restrict__ w1,
                                                  const float* __restrict__ w2,
                                                  const float* __restrict__ w3,
                                                  unsigned short* __restrict__ wT1,
                                                  unsigned short* __restrict__ wT2,
                                                  unsigned short* __restrict__ wT3) {
    int idx = blockIdx.x * 256 + threadIdx.x;
    const float* w; unsigned short* wT; int CIN, CPLOG, SUB, COLOG;
    if (idx < 30720) { w = w1; wT = wT1; CIN = 14; CPLOG = 4; SUB = 3; COLOG = 6; }
    else if (idx < 235520) { idx -= 30720; w = w2; wT = wT2; CIN = 64; CPLOG = 6; SUB = 10; COLOG = 7; }
    else if (idx < 1054720) { idx -= 235520; w = w3; wT = wT3; CIN = 128; CPLOG = 7; SUB = 20; COLOG = 8; }
    else return;
    int kk = idx & 31;
    int co = (idx >> 5) & ((1 << COLOG) - 1);
    int s = idx >> (5 + COLOG);
    int kh = s / SUB, sub = s - kh * SUB;
    int kidx = sub * 32 + kk;
    int kw = kidx >> CPLOG;
    int ci = kidx & ((1 << CPLOG) - 1);
    float v = (kw < 5 && ci < CIN) ? w[((size_t)(co * CIN + ci) * 5 + kh) * 5 + kw] : 0.f;
    wT[idx] = f2bf(v);
}

// ------------------------------------------- implicit-GEMM MFMA conv --------
// NW-wave blocks. Each wave: 64 px (4 f-frags) x NT*16 co -> 4*NT MFMA/step.
// A loaded directly from padded NHWC global (per-lane, coalesced). B staged
// cooperatively into double-buffered LDS, ONE barrier per CH-step chunk.
// Fused BN stats: block-local LDS reduce, then 1 atomic per channel per block.
template <int CP, int COUT, int HP, int LOG_OHW, int LOG_OW, int SUB,
          int NCO, int NT, int CH, int NW>
__global__ __launch_bounds__(NW * 64) void conv_mfma(
        const unsigned short* __restrict__ inP,
        const unsigned short* __restrict__ wT,
        float* __restrict__ outX,
        float* __restrict__ stacc) {
    constexpr int NSTEP = 5 * SUB;
    constexpr int NCHUNK = NSTEP / CH;
    constexpr int COT = NT * 16;
    constexpr int NSTG = (CH * COT * 4) / (NW * 64);
    static_assert(NSTEP % CH == 0, "CH must divide NSTEP");
    static_assert((CH * COT * 4) % (NW * 64) == 0, "staging must tile evenly");
    __shared__ short Bs[2][CH][COT][32];
    __shared__ float sred[NW][2][COT];
    int tid = threadIdx.x;
    int wave = tid >> 6, lane = tid & 63, q = lane >> 4, l16 = lane & 15;
    int bm = blockIdx.x / NCO, bco = blockIdx.x % NCO;

    const short* aB[4];
#pragma unroll
    for (int f = 0; f < 4; ++f) {
        int m = bm * (NW * 64) + wave * 64 + f * 16 + l16;
        int b = m >> LOG_OHW;
        int ohw = m & ((1 << LOG_OHW) - 1);
        int oh = ohw >> LOG_OW, ow = ohw & ((1 << LOG_OW) - 1);
        aB[f] = (const short*)inP + ((size_t)((b * HP + 2 * oh) * HP + 2 * ow)) * CP + q * 8;
    }
    const short* bgbase = (const short*)wT + (size_t)bco * COT * 32;

    floatx4 acc[4][NT];
#pragma unroll
    for (int f = 0; f < 4; ++f)
#pragma unroll
        for (int nt = 0; nt < NT; ++nt) acc[f][nt] = (floatx4){0.f, 0.f, 0.f, 0.f};

    short8 nb[NSTG];
    // stage chunk 0
#pragma unroll
    for (int i = 0; i < NSTG; ++i) {
        int v = tid + i * NW * 64;
        int s = v / (COT * 4);
        int rem = v - s * (COT * 4);
        nb[i] = *(const short8*)(bgbase + ((size_t)s * COUT) * 32 + rem * 8);
    }
#pragma unroll
    for (int i = 0; i < NSTG; ++i) {
        int v = tid + i * NW * 64;
        int s = v / (COT * 4);
        int rem = v - s * (COT * 4);
        *(short8*)((short*)&Bs[0][s][0][0] + rem * 8) = nb[i];
    }
    __syncthreads();

    for (int chunk = 0; chunk < NCHUNK; ++chunk) {
        int cur = chunk & 1;
        if (chunk + 1 < NCHUNK) {
            int step0 = (chunk + 1) * CH;
#pragma unroll
            for (int i = 0; i < NSTG; ++i) {
                int v = tid + i * NW * 64;
                int s = v / (COT * 4);
                int rem = v - s * (COT * 4);
                nb[i] = *(const short8*)(bgbase + ((size_t)(step0 + s) * COUT) * 32 + rem * 8);
            }
        }
#pragma unroll
        for (int s = 0; s < CH; ++s) {
            int step = chunk * CH + s;
            int kh = step / SUB, sub = step - kh * SUB;
            short8 af[4];
#pragma unroll
            for (int f = 0; f < 4; ++f)
                af[f] = *(const short8*)(aB[f] + (size_t)(kh * HP) * CP + sub * 32);
#pragma unroll
            for (int nt = 0; nt < NT; ++nt) {
                short8 bf = *(const short8*)&Bs[cur][s][nt * 16 + l16][q * 8];
#pragma unroll
                for (int f = 0; f < 4; ++f)
                    acc[f][nt] = __builtin_amdgcn_mfma_f32_16x16x32_bf16(af[f], bf, acc[f][nt], 0, 0, 0);
            }
        }
        if (chunk + 1 < NCHUNK) {
#pragma unroll
            for (int i = 0; i < NSTG; ++i) {
                int v = tid + i * NW * 64;
                int s = v / (COT * 4);
                int rem = v - s * (COT * 4);
                *(short8*)((short*)&Bs[cur ^ 1][s][0][0] + rem * 8) = nb[i];
            }
            __syncthreads();
        }
    }
    // output
#pragma unroll
    for (int f = 0; f < 4; ++f)
#pragma unroll
        for (int nt = 0; nt < NT; ++nt)
#pragma unroll
            for (int rg = 0; rg < 4; ++rg) {
                int mg = bm * (NW * 64) + wave * 64 + f * 16 + q * 4 + rg;
                int co = bco * COT + nt * 16 + l16;
                outX[(size_t)mg * COUT + co] = acc[f][nt][rg];
            }
    // fused BN stats: wave shfl-reduce -> LDS -> one atomic per co per block
#pragma unroll
    for (int nt = 0; nt < NT; ++nt) {
        float s = 0.f, s2 = 0.f;
#pragma unroll
        for (int f = 0; f < 4; ++f)
#pragma unroll
            for (int rg = 0; rg < 4; ++rg) {
                float v = acc[f][nt][rg];
                s += v; s2 = fmaf(v, v, s2);
            }
        s += __shfl_xor(s, 16); s += __shfl_xor(s, 32);
        s2 += __shfl_xor(s2, 16); s2 += __shfl_xor(s2, 32);
        if (q == 0) {
            sred[wave][0][nt * 16 + l16] = s;
            sred[wave][1][nt * 16 + l16] = s2;
        }
    }
    __syncthreads();
    if (tid < COT) {
        float ts = 0.f, ts2 = 0.f;
#pragma unroll
        for (int w = 0; w < NW; ++w) { ts += sred[w][0][tid]; ts2 += sred[w][1][tid]; }
        atomicAdd(&stacc[bco * COT + tid], ts);
        atomicAdd(&stacc[COUT + bco * COT + tid], ts2);
    }
}

// --------------------------------------------------- conv4 split-K GEMM -----
__global__ __launch_bounds__(256) void conv4_mfma(const unsigned short* __restrict__ A,
                                                  const float* __restrict__ w4,
                                                  float* __restrict__ h4) {
    constexpr int CH = 4, NCHUNK = 8;
    __shared__ short Bs[CH][64][40];
    int tid = threadIdx.x;
    int bco = blockIdx.x & 15;
    int ks = blockIdx.x >> 4;
    int wave = tid >> 6, lane = tid & 63, q = lane >> 4, l16 = lane & 15;
    const short* aBase = (const short*)A + (size_t)(wave * 16 + l16) * 16384 + ks * 1024 + q * 8;
    int r = tid >> 2, cc = tid & 3;
    const float* bg = w4 + (size_t)(bco * 64 + r) * 16384 + ks * 1024 + cc * 8;

    floatx4 acc[4];
#pragma unroll
    for (int nt = 0; nt < 4; ++nt) acc[nt] = (floatx4){0.f, 0.f, 0.f, 0.f};

    short8 nb[CH];
#pragma unroll
    for (int s = 0; s < CH; ++s) {
        float4 b0 = *(const float4*)(bg + s * 32);
        float4 b1 = *(const float4*)(bg + s * 32 + 4);
        nb[s][0] = (short)f2bf(b0.x); nb[s][1] = (short)f2bf(b0.y);
        nb[s][2] = (short)f2bf(b0.z); nb[s][3] = (short)f2bf(b0.w);
        nb[s][4] = (short)f2bf(b1.x); nb[s][5] = (short)f2bf(b1.y);
        nb[s][6] = (short)f2bf(b1.z); nb[s][7] = (short)f2bf(b1.w);
    }
#pragma unroll
    for (int s = 0; s < CH; ++s) *(short8*)&Bs[s][r][cc * 8] = nb[s];
    __syncthreads();

    for (int chunk = 0; chunk < NCHUNK; ++chunk) {
        bool has_next = (chunk + 1 < NCHUNK);
        if (has_next) {
#pragma unroll
            for (int s = 0; s < CH; ++s) {
                int step = (chunk + 1) * CH + s;
                float4 b0 = *(const float4*)(bg + step * 32);
                float4 b1 = *(const float4*)(bg + step * 32 + 4);
                nb[s][0] = (short)f2bf(b0.x); nb[s][1] = (short)f2bf(b0.y);
                nb[s][2] = (short)f2bf(b0.z); nb[s][3] = (short)f2bf(b0.w);
                nb[s][4] = (short)f2bf(b1.x); nb[s][5] = (short)f2bf(b1.y);
                nb[s][6] = (short)f2bf(b1.z); nb[s][7] = (short)f2bf(b1.w);
            }
        }
#pragma unroll
        for (int s = 0; s < CH; ++s) {
            int step = chunk * CH + s;
            short8 af = *(const short8*)(aBase + step * 32);
#pragma unroll
            for (int nt = 0; nt < 4; ++nt) {
                short8 bf = *(const short8*)&Bs[s][nt * 16 + l16][q * 8];
                acc[nt] = __builtin_amdgcn_mfma_f32_16x16x32_bf16(af, bf, acc[nt], 0, 0, 0);
            }
        }
        if (has_next) {
            __syncthreads();
#pragma unroll
            for (int s = 0; s < CH; ++s) *(short8*)&Bs[s][r][cc * 8] = nb[s];
            __syncthreads();
        }
    }
#pragma unroll
    for (int nt = 0; nt < 4; ++nt) {
#pragma unroll
        for (int rg = 0; rg < 4; ++rg) {
            int mg = wave * 16 + q * 4 + rg;
            int co = bco * 64 + nt * 16 + l16;
            atomicAdd(&h4[(size_t)mg * 1024 + co], acc[nt][rg]);
        }
    }
}

// ----------------------------------------------------------- batch stats ----
__global__ __launch_bounds__(256) void stats_part(const float* __restrict__ X,
                                                  float* __restrict__ acc,
                                                  int CO, int R, int RPB, int CGLOG) {
    int tid = threadIdx.x;
    int cg = blockIdx.x & ((1 << CGLOG) - 1);
    int rb = blockIdx.x >> CGLOG;
    int c = (cg << 6) + (tid & 63);
    int w = tid >> 6;
    float s = 0.f, s2 = 0.f;
    int rend = min(R, (rb + 1) * RPB);
    for (int r = rb * RPB + w; r < rend; r += 4) {
        float v = X[(size_t)r * CO + c];
        s += v; s2 += v * v;
    }
    __shared__ float ls[4][64], ls2[4][64];
    ls[w][tid & 63] = s; ls2[w][tid & 63] = s2;
    __syncthreads();
    if (tid < 64) {
        float ts = ls[0][tid] + ls[1][tid] + ls[2][tid] + ls[3][tid];
        float ts2 = ls2[0][tid] + ls2[1][tid] + ls2[2][tid] + ls2[3][tid];
        int cc = (cg << 6) + tid;
        atomicAdd(&acc[cc], ts);
        atomicAdd(&acc[CO + cc], ts2);
    }
}

// ------------------- BN(inline finalize) + lrelu + pad + bf16 (NHWC) --------
__global__ __launch_bounds__(256) void bnpad_kernel(const float* __restrict__ X,
                                                    const float* __restrict__ stacc,
                                                    const float* __restrict__ g,
                                                    const float* __restrict__ bb,
                                                    unsigned short* __restrict__ out,
                                                    int CO_LOG, int OH, int OHP,
                                                    float invN, int total) {
    int idx = blockIdx.x * 256 + threadIdx.x;
    if (idx >= total) return;
    int CO = 1 << CO_LOG;
    int c = idx & (CO - 1);
    float mean = stacc[c] * invN;
    float var = fmaxf(stacc[CO + c] * invN - mean * mean, 0.f);
    float sc = g[c] * rsqrtf(var + EPS);
    float sh = bb[c] - mean * sc;
    int t = idx >> CO_LOG;
    int x = t % OHP; t /= OHP;
    int y = t % OHP; int b = t / OHP;
    unsigned short v = 0;
    if (y >= 2 && y < OH + 2 && x >= 2 && x < OH + 2) {
        float f = X[(((size_t)(b * OH + (y - 2)) * OH + (x - 2)) << CO_LOG) + c];
        f = f * sc + sh;
        f = f >= 0.f ? f : NEG * f;
        v = f2bf(f);
    }
    out[idx] = v;
}

// -------- BN(inline finalize) + lrelu + bf16, NHWC -> NCHW (conv4 input) ----
__global__ __launch_bounds__(256) void bn_nchw_kernel(const float* __restrict__ X,
                                                      const float* __restrict__ stacc,
                                                      const float* __restrict__ g,
                                                      const float* __restrict__ bb,
                                                      unsigned short* __restrict__ out,
                                                      int total) {
    int idx = blockIdx.x * 256 + threadIdx.x;
    if (idx >= total) return;
    int hw = idx & 63;
    int ci = (idx >> 6) & 255;
    int b = idx >> 14;
    float mean = stacc[ci] * (1.f / 4096.f);
    float var = fmaxf(stacc[256 + ci] * (1.f / 4096.f) - mean * mean, 0.f);
    float sc = g[ci] * rsqrtf(var + EPS);
    float sh = bb[ci] - mean * sc;
    float f = X[((size_t)(b * 64 + hw)) * 256 + ci] * sc + sh;
    f = f >= 0.f ? f : NEG * f;
    out[idx] = f2bf(f);
}

// -------------------------------------- conv5 (inline BN4 finalize) ---------
__global__ __launch_bounds__(256) void conv5_kernel(const float* __restrict__ X,
                                                    const float* __restrict__ stacc,
                                                    const float* __restrict__ g,
                                                    const float* __restrict__ bb,
                                                    const float* __restrict__ w5,
                                                    const float* __restrict__ b5,
                                                    float* __restrict__ out) {
    int b = blockIdx.x, tid = threadIdx.x;
    float s = 0.f;
    for (int c = tid; c < 1024; c += 256) {
        float mean = stacc[c] * (1.f / 64.f);
        float var = fmaxf(stacc[1024 + c] * (1.f / 64.f) - mean * mean, 0.f);
        float sc = g[c] * rsqrtf(var + EPS);
        float sh = bb[c] - mean * sc;
        float f = X[(size_t)b * 1024 + c] * sc + sh;
        f = f >= 0.f ? f : NEG * f;
        s = fmaf(f, w5[c], s);
    }
#pragma unroll
    for (int off = 32; off > 0; off >>= 1) s += __shfl_down(s, off);
    __shared__ float ls[4];
    if ((tid & 63) == 0) ls[tid >> 6] = s;
    __syncthreads();
    if (tid == 0) out[b] = ls[0] + ls[1] + ls[2] + ls[3] + b5[0];
}

// ----------------------------------------------------------------- launch ---
extern "C" void kernel_launch(void* const* d_in, const int* in_sizes, int n_in,
                              void* d_out, int out_size, void* d_ws, size_t ws_size,
                              hipStream_t stream) {
    (void)in_sizes; (void)n_in; (void)out_size; (void)ws_size;
    const float* input_data = (const float*)d_in[0];
    const float* w1 = (const float*)d_in[2];
    const float* g1 = (const float*)d_in[3];
    const float* b1 = (const float*)d_in[4];
    const float* w2 = (const float*)d_in[5];
    const float* g2 = (const float*)d_in[6];
    const float* b2 = (const float*)d_in[7];
    const float* w3 = (const float*)d_in[8];
    const float* g3 = (const float*)d_in[9];
    const float* b3 = (const float*)d_in[10];
    const float* w4 = (const float*)d_in[11];
    const float* g4 = (const float*)d_in[12];
    const float* b4 = (const float*)d_in[13];
    const float* w5 = (const float*)d_in[14];
    const float* b5 = (const float*)d_in[15];

    char* ws = (char*)d_ws;
    float* regA = (float*)ws;               // 16.8 MB: conv1out / conv3out
    char* wsB = ws + 16777216;              // 10.7 MB: pad1 / pad2
    char* wsC = wsB + 10616832;             // 9.5 MB: rendered / conv2out / a4
    char* wsD = wsC + 9469952;
    float* h4  = (float*)wsD;                               // 262,144 B
    float* st1 = (float*)(wsD + 262144);                    // 512 B  (64*2)
    float* st2 = (float*)(wsD + 262656);                    // 1024 B (128*2)
    float* st3 = (float*)(wsD + 263680);                    // 2048 B (256*2)
    float* st4 = (float*)(wsD + 265728);                    // 8192 B (1024*2)
    unsigned short* wT1 = (unsigned short*)(wsD + 274432);  // 61,440 B
    unsigned short* wT2 = (unsigned short*)(wsD + 335872);  // 409,600 B
    unsigned short* wT3 = (unsigned short*)(wsD + 745472);  // 1,638,400 B

    unsigned short* rendered = (unsigned short*)wsC;
    float* conv1out = regA;
    unsigned short* pad1 = (unsigned short*)wsB;
    float* conv2out = (float*)wsC;
    unsigned short* pad2 = (unsigned short*)wsB;
    float* conv3out = regA;
    unsigned short* a4 = (unsigned short*)wsC;

    // one memset covers h4 + all stat accumulators
    hipMemsetAsync(wsD, 0, 273920, stream);
    wtrans_all<<<4120, 256, 0, stream>>>(w1, w2, w3, wT1, wT2, wT3);
    render_kernel<<<1024, 256, 0, stream>>>(input_data, rendered);

    // conv1: [65536,480]x[480,64] — 256 blocks x 4 waves, NT=4, CH=5 (3 chunks)
    conv_mfma<16, 64, 68, 10, 5, 3, 1, 4, 5, 4><<<256, 256, 0, stream>>>(rendered, wT1, conv1out, st1);
    bnpad_kernel<<<20736, 256, 0, stream>>>(conv1out, st1, g1, b1, pad1, 6, 32, 36, 1.f / 65536.f, 5308416);

    // conv2: [16384,1600]x[1600,128] — 64m x 4co = 256 blocks, NT=2, CH=10 (5 chunks)
    conv_mfma<64, 128, 36, 8, 4, 10, 4, 2, 10, 4><<<256, 256, 0, stream>>>(pad1, wT2, conv2out, st2);
    bnpad_kernel<<<12800, 256, 0, stream>>>(conv2out, st2, g2, b2, pad2, 7, 16, 20, 1.f / 16384.f, 3276800);

    // conv3: [4096,3200]x[3200,256] — 32m x 8co = 256 blocks of 2 waves, NT=2, CH=10
    conv_mfma<128, 256, 20, 6, 3, 20, 8, 2, 10, 2><<<256, 128, 0, stream>>>(pad2, wT3, conv3out, st3);
    bn_nchw_kernel<<<4096, 256, 0, stream>>>(conv3out, st3, g3, b3, a4, 1048576);

    // conv4: [64,16384] x [1024,16384]^T -> [64,1024], split-K=16
    conv4_mfma<<<256, 256, 0, stream>>>(a4, w4, h4);
    stats_part<<<16, 256, 0, stream>>>(h4, st4, 1024, 64, 64, 4);

    // conv5 (inline BN4)
    conv5_kernel<<<64, 256, 0, stream>>>(h4, st4, g4, b4, w5, b5, (float*)d_out);
}